// Round 3
// baseline (3842.849 us; speedup 1.0000x reference)
//
#include <hip/hip_runtime.h>
#include <hip/hip_bf16.h>
#include <math.h>

// Problem constants
// B=4, T=2048, C=1024, H=16, HD=64, M = B*T = 8192
// ws layout (floats): Qh[64][2048][64] | Kh | Vh | Oh  (each 8,388,608 floats; 128MB total)

#define M_TOT   8192
#define C_DIM   1024
#define T_DIM   2048
#define NH      16
#define HD      64
#define BHT     (NH * 4)        // B*H = 64

// ---------------------------------------------------------------------------
// Kernel 1: fused QKV projection.  C_virtual = x @ [Wq | Wk | Wv]  (N = 3072)
// 128x128 block tile, BK=8, 8x8 per thread (split 4+4 columns to avoid the
// 4-way LDS bank conflict on B reads), 256 threads.
// Output written directly in head-major layout [B*H, T, 64].
// ---------------------------------------------------------------------------
__global__ __launch_bounds__(256, 2) void qkv_gemm(
    const float* __restrict__ x,
    const float* __restrict__ Wq,
    const float* __restrict__ Wk,
    const float* __restrict__ Wv,
    float* __restrict__ Qh,
    float* __restrict__ Kh,
    float* __restrict__ Vh)
{
    __shared__ float As[8][132];   // [k][m], padded
    __shared__ float Bs[8][132];   // [k][n], padded

    const int tid = threadIdx.x;
    const int m0  = blockIdx.x * 128;
    const int bn  = blockIdx.y;          // 0..23
    const int which = bn >> 3;           // 0=Q,1=K,2=V
    const int nn0 = (bn & 7) * 128;      // column offset within the 1024-wide W

    const float* W   = (which == 0) ? Wq : ((which == 1) ? Wk : Wv);
    float*       out = (which == 0) ? Qh : ((which == 1) ? Kh : Vh);

    const int arow = tid >> 1, aq = tid & 1;   // A tile: 128 rows x 2 quads
    const int brow = tid >> 5, bq = tid & 31;  // B tile: 8 rows x 32 quads

    const float* aptr = x + (size_t)(m0 + arow) * C_DIM + aq * 4;
    const float* bptr = W + (size_t)brow * C_DIM + nn0 + bq * 4;

    const int tx = tid & 15, ty = tid >> 4;

    float acc[8][8];
    #pragma unroll
    for (int i = 0; i < 8; ++i)
        #pragma unroll
        for (int j = 0; j < 8; ++j) acc[i][j] = 0.f;

    float4 av = *(const float4*)(aptr);
    float4 bv = *(const float4*)(bptr);

    for (int kt = 0; kt < 128; ++kt) {
        __syncthreads();
        As[aq * 4 + 0][arow] = av.x;
        As[aq * 4 + 1][arow] = av.y;
        As[aq * 4 + 2][arow] = av.z;
        As[aq * 4 + 3][arow] = av.w;
        *(float4*)&Bs[brow][bq * 4] = bv;
        __syncthreads();

        if (kt + 1 < 128) {  // issue next-tile loads before compute (latency hiding)
            av = *(const float4*)(aptr + (kt + 1) * 8);
            bv = *(const float4*)(bptr + (size_t)(kt + 1) * 8 * C_DIM);
        }

        #pragma unroll
        for (int kk = 0; kk < 8; ++kk) {
            float a[8], b[8];
            #pragma unroll
            for (int i = 0; i < 8; ++i) a[i] = As[kk][ty * 8 + i];
            #pragma unroll
            for (int j = 0; j < 4; ++j) {
                b[j]     = Bs[kk][tx * 4 + j];        // cols nn0 + tx*4 + j
                b[4 + j] = Bs[kk][64 + tx * 4 + j];   // cols nn0 + 64 + tx*4 + j
            }
            #pragma unroll
            for (int i = 0; i < 8; ++i)
                #pragma unroll
                for (int j = 0; j < 8; ++j)
                    acc[i][j] = fmaf(a[i], b[j], acc[i][j]);
        }
    }

    // write head-major: [(b*16+h)*2048 + t]*64 + d
    const int ha = nn0 >> 6;         // even head index (nn0 multiple of 128)
    const int d0 = tx * 4;
    #pragma unroll
    for (int i = 0; i < 8; ++i) {
        const int m = m0 + ty * 8 + i;
        const int b = m >> 11, t = m & 2047;
        float* opA = out + (size_t)((b * NH + ha    ) * T_DIM + t) * HD + d0;
        float* opB = out + (size_t)((b * NH + ha + 1) * T_DIM + t) * HD + d0;
        *(float4*)opA = make_float4(acc[i][0], acc[i][1], acc[i][2], acc[i][3]);
        *(float4*)opB = make_float4(acc[i][4], acc[i][5], acc[i][6], acc[i][7]);
    }
}

// ---------------------------------------------------------------------------
// Kernel 2: causal attention, fp32, LDS-free.
// One q-row per thread, 64-thread (1-wave) blocks, 2048 blocks total so the
// whole grid is co-resident (kills the round-2 occupancy/grid-starvation).
// K/V rows are wave-uniform addresses -> broadcast loads served by L1/L2
// (per-(b,h) K/V is 1 MB, L2-resident). Heavy diagonal blocks dispatch first.
// ---------------------------------------------------------------------------
__global__ __launch_bounds__(64, 2) void attn_kernel(
    const float* __restrict__ Qh,
    const float* __restrict__ Kh,
    const float* __restrict__ Vh,
    float* __restrict__ Oh)
{
    const int tid = threadIdx.x;
    const int bid = blockIdx.x;
    const int bh  = bid & (BHT - 1);                 // b*16+h
    const int qt  = (T_DIM / 64 - 1) - (bid >> 6);   // heavy-first: qt=31 dispatches first
    const int row = qt * 64 + tid;

    const float* qp = Qh + ((size_t)bh * T_DIM + row) * HD;
    float q[64];
    #pragma unroll
    for (int d = 0; d < 64; d += 4) {
        float4 v = *(const float4*)(qp + d);
        q[d] = v.x; q[d + 1] = v.y; q[d + 2] = v.z; q[d + 3] = v.w;
    }

    float o[64];
    #pragma unroll
    for (int d = 0; d < 64; ++d) o[d] = 0.f;
    float mx = -INFINITY, l = 0.f;

    const float* kb = Kh + (size_t)bh * T_DIM * HD;
    const float* vb = Vh + (size_t)bh * T_DIM * HD;

    const int kend = qt * 64 + 63;   // max row in this wave (uniform bound)
    for (int kk = 0; kk <= kend; ++kk) {
        const float* kr = kb + (size_t)kk * HD;
        float s0 = 0.f, s1 = 0.f, s2 = 0.f, s3 = 0.f;
        #pragma unroll
        for (int d = 0; d < 64; d += 4) {
            float4 kv = *(const float4*)(kr + d);
            s0 = fmaf(q[d],     kv.x, s0);
            s1 = fmaf(q[d + 1], kv.y, s1);
            s2 = fmaf(q[d + 2], kv.z, s2);
            s3 = fmaf(q[d + 3], kv.w, s3);
        }
        float s = ((s0 + s1) + (s2 + s3)) * 0.125f;   // 1/sqrt(64)
        if (kk > row) s = -3.0e38f;                   // causal mask -> w=0
        if (s > mx) {                                 // rare rescale on new max
            float c = __expf(mx - s);
            #pragma unroll
            for (int d = 0; d < 64; ++d) o[d] *= c;
            l *= c;
            mx = s;
        }
        float w = __expf(s - mx);
        l += w;
        const float* vr = vb + (size_t)kk * HD;
        #pragma unroll
        for (int d = 0; d < 64; d += 4) {
            float4 vv = *(const float4*)(vr + d);
            o[d]     = fmaf(w, vv.x, o[d]);
            o[d + 1] = fmaf(w, vv.y, o[d + 1]);
            o[d + 2] = fmaf(w, vv.z, o[d + 2]);
            o[d + 3] = fmaf(w, vv.w, o[d + 3]);
        }
    }

    const float inv = 1.0f / l;
    float* op = Oh + ((size_t)bh * T_DIM + row) * HD;
    #pragma unroll
    for (int d = 0; d < 64; d += 4) {
        *(float4*)(op + d) = make_float4(o[d] * inv, o[d + 1] * inv,
                                         o[d + 2] * inv, o[d + 3] * inv);
    }
}

// ---------------------------------------------------------------------------
// Kernel 3: output projection  out = Oh(head-major) @ Wc + bc
// ---------------------------------------------------------------------------
__global__ __launch_bounds__(256, 2) void out_gemm(
    const float* __restrict__ Oh,
    const float* __restrict__ Wc,
    const float* __restrict__ bc,
    float* __restrict__ out)
{
    __shared__ float As[8][132];
    __shared__ float Bs[8][132];

    const int tid = threadIdx.x;
    const int m0  = blockIdx.x * 128;
    const int nn0 = blockIdx.y * 128;

    const int arow = tid >> 1, aq = tid & 1;
    const int brow = tid >> 5, bq = tid & 31;

    const int am = m0 + arow;
    const size_t aBase = (size_t)((am >> 11) * NH) * (size_t)(T_DIM * HD)
                       + (size_t)(am & 2047) * HD;
    const float* bptr = Wc + (size_t)brow * C_DIM + nn0 + bq * 4;

    const int tx = tid & 15, ty = tid >> 4;

    float acc[8][8];
    #pragma unroll
    for (int i = 0; i < 8; ++i)
        #pragma unroll
        for (int j = 0; j < 8; ++j) acc[i][j] = 0.f;

    int kcol = aq * 4;
    float4 av = *(const float4*)(Oh + aBase + (size_t)(kcol >> 6) * (T_DIM * HD) + (kcol & 63));
    float4 bv = *(const float4*)(bptr);

    for (int kt = 0; kt < 128; ++kt) {
        __syncthreads();
        As[aq * 4 + 0][arow] = av.x;
        As[aq * 4 + 1][arow] = av.y;
        As[aq * 4 + 2][arow] = av.z;
        As[aq * 4 + 3][arow] = av.w;
        *(float4*)&Bs[brow][bq * 4] = bv;
        __syncthreads();

        if (kt + 1 < 128) {
            kcol = (kt + 1) * 8 + aq * 4;
            av = *(const float4*)(Oh + aBase + (size_t)(kcol >> 6) * (T_DIM * HD) + (kcol & 63));
            bv = *(const float4*)(bptr + (size_t)(kt + 1) * 8 * C_DIM);
        }

        #pragma unroll
        for (int kk = 0; kk < 8; ++kk) {
            float a[8], b[8];
            #pragma unroll
            for (int i = 0; i < 8; ++i) a[i] = As[kk][ty * 8 + i];
            #pragma unroll
            for (int j = 0; j < 4; ++j) {
                b[j]     = Bs[kk][tx * 4 + j];
                b[4 + j] = Bs[kk][64 + tx * 4 + j];
            }
            #pragma unroll
            for (int i = 0; i < 8; ++i)
                #pragma unroll
                for (int j = 0; j < 8; ++j)
                    acc[i][j] = fmaf(a[i], b[j], acc[i][j]);
        }
    }

    const int col0 = nn0 + tx * 4;       // group A cols; group B at col0+64
    float bias[8];
    #pragma unroll
    for (int j = 0; j < 4; ++j) {
        bias[j]     = bc[col0 + j];
        bias[4 + j] = bc[col0 + 64 + j];
    }

    #pragma unroll
    for (int i = 0; i < 8; ++i) {
        const int m = m0 + ty * 8 + i;
        float* op = out + (size_t)m * C_DIM;
        *(float4*)(op + col0)      = make_float4(acc[i][0] + bias[0], acc[i][1] + bias[1],
                                                 acc[i][2] + bias[2], acc[i][3] + bias[3]);
        *(float4*)(op + col0 + 64) = make_float4(acc[i][4] + bias[4], acc[i][5] + bias[5],
                                                 acc[i][6] + bias[6], acc[i][7] + bias[7]);
    }
}

// ---------------------------------------------------------------------------
extern "C" void kernel_launch(void* const* d_in, const int* in_sizes, int n_in,
                              void* d_out, int out_size, void* d_ws, size_t ws_size,
                              hipStream_t stream)
{
    const float* x  = (const float*)d_in[0];
    const float* Wq = (const float*)d_in[1];
    const float* Wk = (const float*)d_in[2];
    const float* Wv = (const float*)d_in[3];
    const float* Wc = (const float*)d_in[4];
    const float* bc = (const float*)d_in[5];
    float* out = (float*)d_out;

    float* ws = (float*)d_ws;
    const size_t PLANE = (size_t)M_TOT * C_DIM;  // 8,388,608 floats
    float* Qh = ws;
    float* Kh = ws + PLANE;
    float* Vh = ws + 2 * PLANE;
    float* Oh = ws + 3 * PLANE;

    {
        dim3 grid(M_TOT / 128, 24);   // 24 = 3 * (1024/128)
        qkv_gemm<<<grid, 256, 0, stream>>>(x, Wq, Wk, Wv, Qh, Kh, Vh);
    }
    {
        dim3 grid(T_DIM / 64 * BHT);  // 2048 one-wave blocks, heavy-first
        attn_kernel<<<grid, 64, 0, stream>>>(Qh, Kh, Vh, Oh);
    }
    {
        dim3 grid(M_TOT / 128, C_DIM / 128);  // (64, 8)
        out_gemm<<<grid, 256, 0, stream>>>(Oh, Wc, bc, out);
    }
}

// Round 5
// 1575.389 us; speedup vs baseline: 2.4393x; 2.4393x over previous
//
#include <hip/hip_runtime.h>
#include <hip/hip_bf16.h>
#include <math.h>

// Problem constants
// B=4, T=2048, C=1024, H=16, HD=64, M = B*T = 8192
// ws layout: Qh bf16[64][2048][64] | Kh bf16 | Vt bf16[64][64][2048] | Oh f32[64][2048][64]

#define M_TOT   8192
#define C_DIM   1024
#define T_DIM   2048
#define NH      16
#define HD      64
#define BHT     (NH * 4)        // B*H = 64

typedef short  bf16x8 __attribute__((ext_vector_type(8)));
typedef ushort u16x8  __attribute__((ext_vector_type(8)));
typedef float  f32x4  __attribute__((ext_vector_type(4)));

static __device__ __forceinline__ ushort f2bf(float f) {
    union { __hip_bfloat16 h; ushort u; } cv;
    cv.h = __float2bfloat16(f);
    return cv.u;
}

// ---------------------------------------------------------------------------
// Kernel 1: fused QKV projection (fp32 math), bf16 outputs.
// Q,K -> head-major [B*H][T][64] bf16.  V -> transposed [B*H][64 d][T] bf16.
// 128x128 tile, BK=8, 8x8/thread (4+4 column split), 256 threads.
// ---------------------------------------------------------------------------
__global__ __launch_bounds__(256, 2) void qkv_gemm(
    const float* __restrict__ x,
    const float* __restrict__ Wq,
    const float* __restrict__ Wk,
    const float* __restrict__ Wv,
    ushort* __restrict__ Qh,
    ushort* __restrict__ Kh,
    ushort* __restrict__ Vt)
{
    __shared__ float As[8][132];   // [k][m], padded
    __shared__ float Bs[8][132];   // [k][n], padded

    const int tid = threadIdx.x;
    const int m0  = blockIdx.x * 128;
    const int bn  = blockIdx.y;          // 0..23
    const int which = bn >> 3;           // 0=Q,1=K,2=V
    const int nn0 = (bn & 7) * 128;

    const float* W = (which == 0) ? Wq : ((which == 1) ? Wk : Wv);

    const int arow = tid >> 1, aq = tid & 1;
    const int brow = tid >> 5, bq = tid & 31;

    const float* aptr = x + (size_t)(m0 + arow) * C_DIM + aq * 4;
    const float* bptr = W + (size_t)brow * C_DIM + nn0 + bq * 4;

    const int tx = tid & 15, ty = tid >> 4;

    float acc[8][8];
    #pragma unroll
    for (int i = 0; i < 8; ++i)
        #pragma unroll
        for (int j = 0; j < 8; ++j) acc[i][j] = 0.f;

    float4 av = *(const float4*)(aptr);
    float4 bv = *(const float4*)(bptr);

    for (int kt = 0; kt < 128; ++kt) {
        __syncthreads();
        As[aq * 4 + 0][arow] = av.x;
        As[aq * 4 + 1][arow] = av.y;
        As[aq * 4 + 2][arow] = av.z;
        As[aq * 4 + 3][arow] = av.w;
        *(float4*)&Bs[brow][bq * 4] = bv;
        __syncthreads();

        if (kt + 1 < 128) {
            av = *(const float4*)(aptr + (kt + 1) * 8);
            bv = *(const float4*)(bptr + (size_t)(kt + 1) * 8 * C_DIM);
        }

        #pragma unroll
        for (int kk = 0; kk < 8; ++kk) {
            float a[8], b[8];
            #pragma unroll
            for (int i = 0; i < 8; ++i) a[i] = As[kk][ty * 8 + i];
            #pragma unroll
            for (int j = 0; j < 4; ++j) {
                b[j]     = Bs[kk][tx * 4 + j];        // cols nn0 + tx*4 + j
                b[4 + j] = Bs[kk][64 + tx * 4 + j];   // cols nn0 + 64 + tx*4 + j
            }
            #pragma unroll
            for (int i = 0; i < 8; ++i)
                #pragma unroll
                for (int j = 0; j < 8; ++j)
                    acc[i][j] = fmaf(a[i], b[j], acc[i][j]);
        }
    }

    if (which < 2) {
        // Q/K: head-major bf16 [bh][t][64]; cols nn0+tx*4 (head ha) and +64 (head ha+1)
        ushort* out = (which == 0) ? Qh : Kh;
        const int ha = nn0 >> 6;
        const int d0 = tx * 4;
        #pragma unroll
        for (int i = 0; i < 8; ++i) {
            const int m = m0 + ty * 8 + i;
            const int b = m >> 11, t = m & 2047;
            ushort* opA = out + (size_t)((b * NH + ha    ) * T_DIM + t) * HD + d0;
            ushort* opB = out + (size_t)((b * NH + ha + 1) * T_DIM + t) * HD + d0;
            ushort4 pa = make_ushort4(f2bf(acc[i][0]), f2bf(acc[i][1]), f2bf(acc[i][2]), f2bf(acc[i][3]));
            ushort4 pb = make_ushort4(f2bf(acc[i][4]), f2bf(acc[i][5]), f2bf(acc[i][6]), f2bf(acc[i][7]));
            *(ushort4*)opA = pa;
            *(ushort4*)opB = pb;
        }
    } else {
        // V: transposed bf16 [bh*64 + d][T]; thread's 8 cols -> 8 rows of Vt,
        // 8 consecutive t values each -> one 16B store per col.
        const int b = m0 >> 11;              // all 128 rows share one batch
        const int t0 = (m0 & 2047) + ty * 8;
        #pragma unroll
        for (int j = 0; j < 8; ++j) {
            const int col = (j < 4) ? (nn0 + tx * 4 + j) : (nn0 + 64 + tx * 4 + (j - 4));
            const int h = col >> 6, d = col & 63;
            ushort* vp = Vt + ((size_t)(b * NH + h) * HD + d) * T_DIM + t0;
            u16x8 v;
            #pragma unroll
            for (int e = 0; e < 8; ++e) v[e] = f2bf(acc[e][j]);
            *(u16x8*)vp = v;
        }
    }
}

// ---------------------------------------------------------------------------
// Kernel 2: causal flash attention, bf16 MFMA (16x16x32).
// Swapped operands: S^T = mfma(K, Q)  -> per-lane softmax (q = lane&15);
//                   O^T = mfma(V^T, P^T) -> rescale/divide also lane-local.
// 4 waves/block, 16 q-rows/wave, 64 q-rows/block; KV tiles of 64.
// No LDS in main loop (K/Vt L2-resident); LDS transpose only in epilogue.
// ---------------------------------------------------------------------------
__global__ __launch_bounds__(256, 2) void attn_kernel(
    const ushort* __restrict__ Qh,
    const ushort* __restrict__ Kh,
    const ushort* __restrict__ Vt,
    float* __restrict__ Oh)
{
    __shared__ float olds[4][16][68];   // per-wave epilogue transpose

    const int tid  = threadIdx.x;
    const int wave = tid >> 6, lane = tid & 63;
    const int lq   = lane & 15, g = lane >> 4;
    const int bh   = blockIdx.y;
    const int qt   = (T_DIM / 64 - 1) - blockIdx.x;   // heavy-first
    const int q0   = qt * 64;
    const int qw0  = q0 + wave * 16;
    const int q    = qw0 + lq;
    const int ntiles = qt + 1;

    // Q fragments (B-operand: n=lane&15=q, k=d with mapping d = c*32 + g*8 + j)
    const ushort* Qb = Qh + ((size_t)bh * T_DIM + qw0 + lq) * HD;
    bf16x8 qf[2];
    qf[0] = *(const bf16x8*)(Qb + g * 8);
    qf[1] = *(const bf16x8*)(Qb + 32 + g * 8);

    const ushort* Kb = Kh + (size_t)bh * T_DIM * HD;
    const ushort* Vb = Vt + (size_t)bh * HD * T_DIM;

    f32x4 o[4];
    #pragma unroll
    for (int dt = 0; dt < 4; ++dt) { o[dt][0]=0.f; o[dt][1]=0.f; o[dt][2]=0.f; o[dt][3]=0.f; }
    float m = -3.0e38f, l = 0.f;

    for (int kvt = 0; kvt < ntiles; ++kvt) {
        const bool lastt = (kvt == ntiles - 1);

        // --- K fragments (A-operand: m=lane&15=kv row, k=d = c*32 + g*8 + j) ---
        bf16x8 kf[4][2];
        const ushort* Kt = Kb + (size_t)(kvt * 64) * HD;
        #pragma unroll
        for (int kt = 0; kt < 4; ++kt) {
            const ushort* kr = Kt + (size_t)(kt * 16 + lq) * HD + g * 8;
            kf[kt][0] = *(const bf16x8*)(kr);
            kf[kt][1] = *(const bf16x8*)(kr + 32);
        }

        // --- V^T fragments issued early (A-operand for PV):
        //     m=lane&15=d, k=kv = cc*32 + (j>>2)*16 + g*4 + (j&3) ---
        bf16x8 vf[4][2];
        #pragma unroll
        for (int dt = 0; dt < 4; ++dt) {
            const ushort* vr = Vb + (size_t)(dt * 16 + lq) * T_DIM + kvt * 64 + g * 4;
            #pragma unroll
            for (int cc = 0; cc < 2; ++cc) {
                ushort4 lo = *(const ushort4*)(vr + cc * 32);
                ushort4 hi = *(const ushort4*)(vr + cc * 32 + 16);
                bf16x8 v;
                v[0] = (short)lo.x; v[1] = (short)lo.y; v[2] = (short)lo.z; v[3] = (short)lo.w;
                v[4] = (short)hi.x; v[5] = (short)hi.y; v[6] = (short)hi.z; v[7] = (short)hi.w;
                vf[dt][cc] = v;
            }
        }

        // --- S^T = K · Q^T : D[kv_local][q], kv_local = kt*16 + g*4 + r ---
        f32x4 s[4];
        #pragma unroll
        for (int kt = 0; kt < 4; ++kt) {
            f32x4 z; z[0]=0.f; z[1]=0.f; z[2]=0.f; z[3]=0.f;
            z = __builtin_amdgcn_mfma_f32_16x16x32_bf16(kf[kt][0], qf[0], z, 0, 0, 0);
            s[kt] = __builtin_amdgcn_mfma_f32_16x16x32_bf16(kf[kt][1], qf[1], z, 0, 0, 0);
        }

        // --- online softmax (all state lane-local: q = lane&15) ---
        float p[4][4];
        float pmax = -3.0e38f;
        #pragma unroll
        for (int kt = 0; kt < 4; ++kt) {
            #pragma unroll
            for (int r = 0; r < 4; ++r) {
                float v = s[kt][r] * 0.125f;   // 1/sqrt(64)
                if (lastt) {
                    const int kv = kvt * 64 + kt * 16 + g * 4 + r;
                    if (kv > q) v = -3.0e38f;
                }
                p[kt][r] = v;
                pmax = fmaxf(pmax, v);
            }
        }
        pmax = fmaxf(pmax, __shfl_xor(pmax, 16));
        pmax = fmaxf(pmax, __shfl_xor(pmax, 32));
        const float mnew = fmaxf(m, pmax);
        const float cf = __expf(m - mnew);
        m = mnew;

        float rs = 0.f;
        #pragma unroll
        for (int kt = 0; kt < 4; ++kt) {
            #pragma unroll
            for (int r = 0; r < 4; ++r) {
                const float w = __expf(p[kt][r] - mnew);
                p[kt][r] = w;
                rs += w;
            }
        }
        rs += __shfl_xor(rs, 16);
        rs += __shfl_xor(rs, 32);
        l = l * cf + rs;

        #pragma unroll
        for (int dt = 0; dt < 4; ++dt) {
            o[dt][0] *= cf; o[dt][1] *= cf; o[dt][2] *= cf; o[dt][3] *= cf;
        }

        // --- pack P^T (B-operand: n=lane&15=q, k=kv same mapping as vf) ---
        bf16x8 pf[2];
        #pragma unroll
        for (int cc = 0; cc < 2; ++cc) {
            #pragma unroll
            for (int j = 0; j < 8; ++j)
                pf[cc][j] = (short)f2bf(p[cc * 2 + (j >> 2)][j & 3]);
        }

        // --- O^T += V^T · P^T ---
        #pragma unroll
        for (int dt = 0; dt < 4; ++dt) {
            o[dt] = __builtin_amdgcn_mfma_f32_16x16x32_bf16(vf[dt][0], pf[0], o[dt], 0, 0, 0);
            o[dt] = __builtin_amdgcn_mfma_f32_16x16x32_bf16(vf[dt][1], pf[1], o[dt], 0, 0, 0);
        }
    }

    // --- epilogue: divide by l, transpose via per-wave LDS, coalesced store ---
    const float invl = 1.0f / l;
    #pragma unroll
    for (int dt = 0; dt < 4; ++dt) {
        #pragma unroll
        for (int r = 0; r < 4; ++r)
            olds[wave][lq][dt * 16 + g * 4 + r] = o[dt][r] * invl;
    }
    // wave-private LDS region: in-wave lgkmcnt ordering suffices, no barrier.
    #pragma unroll
    for (int pp = 0; pp < 4; ++pp) {
        const int qq = pp * 4 + g;
        float4 v4 = *(const float4*)&olds[wave][qq][lq * 4];
        *(float4*)(Oh + ((size_t)bh * T_DIM + qw0 + qq) * HD + lq * 4) = v4;
    }
}

// ---------------------------------------------------------------------------
// Kernel 3: output projection  out = Oh(head-major, f32) @ Wc + bc
// ---------------------------------------------------------------------------
__global__ __launch_bounds__(256, 2) void out_gemm(
    const float* __restrict__ Oh,
    const float* __restrict__ Wc,
    const float* __restrict__ bc,
    float* __restrict__ out)
{
    __shared__ float As[8][132];
    __shared__ float Bs[8][132];

    const int tid = threadIdx.x;
    const int m0  = blockIdx.x * 128;
    const int nn0 = blockIdx.y * 128;

    const int arow = tid >> 1, aq = tid & 1;
    const int brow = tid >> 5, bq = tid & 31;

    const int am = m0 + arow;
    const size_t aBase = (size_t)((am >> 11) * NH) * (size_t)(T_DIM * HD)
                       + (size_t)(am & 2047) * HD;
    const float* bptr = Wc + (size_t)brow * C_DIM + nn0 + bq * 4;

    const int tx = tid & 15, ty = tid >> 4;

    float acc[8][8];
    #pragma unroll
    for (int i = 0; i < 8; ++i)
        #pragma unroll
        for (int j = 0; j < 8; ++j) acc[i][j] = 0.f;

    int kcol = aq * 4;
    float4 av = *(const float4*)(Oh + aBase + (size_t)(kcol >> 6) * (T_DIM * HD) + (kcol & 63));
    float4 bv = *(const float4*)(bptr);

    for (int kt = 0; kt < 128; ++kt) {
        __syncthreads();
        As[aq * 4 + 0][arow] = av.x;
        As[aq * 4 + 1][arow] = av.y;
        As[aq * 4 + 2][arow] = av.z;
        As[aq * 4 + 3][arow] = av.w;
        *(float4*)&Bs[brow][bq * 4] = bv;
        __syncthreads();

        if (kt + 1 < 128) {
            kcol = (kt + 1) * 8 + aq * 4;
            av = *(const float4*)(Oh + aBase + (size_t)(kcol >> 6) * (T_DIM * HD) + (kcol & 63));
            bv = *(const float4*)(bptr + (size_t)(kt + 1) * 8 * C_DIM);
        }

        #pragma unroll
        for (int kk = 0; kk < 8; ++kk) {
            float a[8], b[8];
            #pragma unroll
            for (int i = 0; i < 8; ++i) a[i] = As[kk][ty * 8 + i];
            #pragma unroll
            for (int j = 0; j < 4; ++j) {
                b[j]     = Bs[kk][tx * 4 + j];
                b[4 + j] = Bs[kk][64 + tx * 4 + j];
            }
            #pragma unroll
            for (int i = 0; i < 8; ++i)
                #pragma unroll
                for (int j = 0; j < 8; ++j)
                    acc[i][j] = fmaf(a[i], b[j], acc[i][j]);
        }
    }

    const int col0 = nn0 + tx * 4;
    float bias[8];
    #pragma unroll
    for (int j = 0; j < 4; ++j) {
        bias[j]     = bc[col0 + j];
        bias[4 + j] = bc[col0 + 64 + j];
    }

    #pragma unroll
    for (int i = 0; i < 8; ++i) {
        const int m = m0 + ty * 8 + i;
        float* op = out + (size_t)m * C_DIM;
        *(float4*)(op + col0)      = make_float4(acc[i][0] + bias[0], acc[i][1] + bias[1],
                                                 acc[i][2] + bias[2], acc[i][3] + bias[3]);
        *(float4*)(op + col0 + 64) = make_float4(acc[i][4] + bias[4], acc[i][5] + bias[5],
                                                 acc[i][6] + bias[6], acc[i][7] + bias[7]);
    }
}

// ---------------------------------------------------------------------------
extern "C" void kernel_launch(void* const* d_in, const int* in_sizes, int n_in,
                              void* d_out, int out_size, void* d_ws, size_t ws_size,
                              hipStream_t stream)
{
    const float* x  = (const float*)d_in[0];
    const float* Wq = (const float*)d_in[1];
    const float* Wk = (const float*)d_in[2];
    const float* Wv = (const float*)d_in[3];
    const float* Wc = (const float*)d_in[4];
    const float* bc = (const float*)d_in[5];
    float* out = (float*)d_out;

    const size_t PLANE = (size_t)M_TOT * C_DIM;  // 8,388,608 elements
    ushort* Qh = (ushort*)d_ws;
    ushort* Kh = Qh + PLANE;
    ushort* Vt = Kh + PLANE;
    float*  Oh = (float*)(Vt + PLANE);   // 48MB offset, f32 plane (32MB)

    {
        dim3 grid(M_TOT / 128, 24);   // 24 = 3 * (1024/128)
        qkv_gemm<<<grid, 256, 0, stream>>>(x, Wq, Wk, Wv, Qh, Kh, Vt);
    }
    {
        dim3 grid(T_DIM / 64, BHT);   // (32, 64); heavy-first in x
        attn_kernel<<<grid, 256, 0, stream>>>(Qh, Kh, Vt, Oh);
    }
    {
        dim3 grid(M_TOT / 128, C_DIM / 128);  // (64, 8)
        out_gemm<<<grid, 256, 0, stream>>>(Oh, Wc, bc, out);
    }
}

// Round 7
// 939.931 us; speedup vs baseline: 4.0884x; 1.6761x over previous
//
#include <hip/hip_runtime.h>
#include <hip/hip_bf16.h>
#include <math.h>

// B=4, T=2048, C=1024, H=16, HD=64, M = B*T = 8192
// ws (ushort units, 128 MiB total):
//   xh,xl [8192][1024] | WTh,WTl [3072][1024] | WcTh,WcTl [1024][1024]
//   Qh,Kh [64][2048][64] | Vt [64][64][2048] | Ohh,Ohl [64][2048][64]

#define M_TOT   8192
#define C_DIM   1024
#define T_DIM   2048
#define NH      16
#define HD      64
#define BHT     (NH * 4)        // B*H = 64

typedef short  bf16x8 __attribute__((ext_vector_type(8)));
typedef ushort u16x8  __attribute__((ext_vector_type(8)));
typedef float  f32x4  __attribute__((ext_vector_type(4)));

static __device__ __forceinline__ ushort f2bf(float f) {
    union { __hip_bfloat16 h; ushort u; } cv;
    cv.h = __float2bfloat16(f);
    return cv.u;
}
static __device__ __forceinline__ float bf2f(ushort u) {
    union { ushort u; __hip_bfloat16 h; } cv;
    cv.u = u;
    return __bfloat162float(cv.h);
}
static __device__ __forceinline__ void gload16(const ushort* g, ushort* l) {
    __builtin_amdgcn_global_load_lds(
        (const __attribute__((address_space(1))) void*)g,
        (__attribute__((address_space(3))) void*)l, 16, 0, 0);
}

// ---------------------------------------------------------------------------
// Decomp 1: x fp32 -> xh/xl bf16 (hi/lo split). 8 elems/thread.
// ---------------------------------------------------------------------------
__global__ __launch_bounds__(256) void decomp_x(
    const float* __restrict__ x, ushort* __restrict__ xh, ushort* __restrict__ xl)
{
    const int i = blockIdx.x * 256 + threadIdx.x;
    const float4 a = ((const float4*)x)[2 * i];
    const float4 b = ((const float4*)x)[2 * i + 1];
    const float v[8] = {a.x, a.y, a.z, a.w, b.x, b.y, b.z, b.w};
    u16x8 h, l;
    #pragma unroll
    for (int e = 0; e < 8; ++e) {
        h[e] = f2bf(v[e]);
        l[e] = f2bf(v[e] - bf2f(h[e]));
    }
    ((u16x8*)xh)[i] = h;
    ((u16x8*)xl)[i] = l;
}

// ---------------------------------------------------------------------------
// Decomp 2: transpose W (fp32 [1024][1024]) -> WT hi/lo bf16 [n][k].
// z selects Wq/Wk/Wv (rows z*1024.. of WTqkv) or Wc (-> WcT).
// ---------------------------------------------------------------------------
__global__ __launch_bounds__(256) void wtrans(
    const float* __restrict__ Wq, const float* __restrict__ Wk,
    const float* __restrict__ Wv, const float* __restrict__ Wc,
    ushort* __restrict__ WTh, ushort* __restrict__ WTl,
    ushort* __restrict__ WcTh, ushort* __restrict__ WcTl)
{
    __shared__ float tile[64][65];
    const int z = blockIdx.z;
    const float* W = (z == 0) ? Wq : (z == 1) ? Wk : (z == 2) ? Wv : Wc;
    const int n0 = blockIdx.x * 64, k0 = blockIdx.y * 64;
    const int tid = threadIdx.x;

    #pragma unroll
    for (int i = 0; i < 4; ++i) {
        const int lin = i * 1024 + tid * 4;
        const int r = lin >> 6, c = lin & 63;
        const float4 v = *(const float4*)(W + (size_t)(k0 + r) * 1024 + n0 + c);
        tile[r][c] = v.x; tile[r][c + 1] = v.y; tile[r][c + 2] = v.z; tile[r][c + 3] = v.w;
    }
    __syncthreads();

    ushort* oh = (z < 3) ? WTh : WcTh;
    ushort* ol = (z < 3) ? WTl : WcTl;
    const size_t rowbase = (z < 3) ? (size_t)z * 1024 : 0;
    #pragma unroll
    for (int i = 0; i < 4; ++i) {
        const int lin = i * 1024 + tid * 4;
        const int rn = lin >> 6, ck = lin & 63;
        ushort4 hv, lv;
        float v0 = tile[ck + 0][rn], v1 = tile[ck + 1][rn];
        float v2 = tile[ck + 2][rn], v3 = tile[ck + 3][rn];
        hv.x = f2bf(v0); lv.x = f2bf(v0 - bf2f(hv.x));
        hv.y = f2bf(v1); lv.y = f2bf(v1 - bf2f(hv.y));
        hv.z = f2bf(v2); lv.z = f2bf(v2 - bf2f(hv.z));
        hv.w = f2bf(v3); lv.w = f2bf(v3 - bf2f(hv.w));
        const size_t off = (rowbase + n0 + rn) * 1024 + k0 + ck;
        *(ushort4*)(oh + off) = hv;
        *(ushort4*)(ol + off) = lv;
    }
}

// ---------------------------------------------------------------------------
// Kernel 1: QKV projection, bf16 MFMA, split-bf16 (AhBh + AlBh + AhBl).
// 128x128 tile, BK=64, 4 waves x (64x64), global_load_lds staging, 2-barrier.
// Outputs Q/K head-major bf16, V transposed bf16.
// ---------------------------------------------------------------------------
__global__ __launch_bounds__(256, 2) void qkv_mfma(
    const ushort* __restrict__ xh, const ushort* __restrict__ xl,
    const ushort* __restrict__ WTh, const ushort* __restrict__ WTl,
    ushort* __restrict__ Qh, ushort* __restrict__ Kh, ushort* __restrict__ Vt)
{
    __shared__ ushort Ah[128 * 64], Al[128 * 64], Bh[128 * 64], Bl[128 * 64]; // 64 KB

    const int tid = threadIdx.x;
    const int wave = tid >> 6, lane = tid & 63, lq = lane & 15, g = lane >> 4;
    const int m0 = blockIdx.x * 128;
    const int n0 = blockIdx.y * 128;            // 0..2944 over WT rows (3072)
    const int wm = wave >> 1, wn = wave & 1;
    const int sm = tid >> 3;                    // staging row (+rd*32)
    const int sk = (tid & 7) * 8;               // staging k offset

    f32x4 acc[4][4];
    #pragma unroll
    for (int i = 0; i < 4; ++i)
        #pragma unroll
        for (int j = 0; j < 4; ++j) { acc[i][j][0]=0.f; acc[i][j][1]=0.f; acc[i][j][2]=0.f; acc[i][j][3]=0.f; }

    for (int kt = 0; kt < 16; ++kt) {
        const int ko = kt * 64 + sk;
        #pragma unroll
        for (int rd = 0; rd < 4; ++rd) {
            const int mm = sm + rd * 32;
            const int lo = rd * 2048 + wave * 512;     // ushort idx, wave-uniform base
            gload16(xh  + (size_t)(m0 + mm) * 1024 + ko, &Ah[lo]);
            gload16(xl  + (size_t)(m0 + mm) * 1024 + ko, &Al[lo]);
            gload16(WTh + (size_t)(n0 + mm) * 1024 + ko, &Bh[lo]);
            gload16(WTl + (size_t)(n0 + mm) * 1024 + ko, &Bl[lo]);
        }
        __syncthreads();

        #pragma unroll
        for (int kc = 0; kc < 2; ++kc) {
            bf16x8 bhf[4], blf[4];
            #pragma unroll
            for (int ni = 0; ni < 4; ++ni) {
                const int row = wn * 64 + ni * 16 + lq;
                bhf[ni] = *(const bf16x8*)&Bh[row * 64 + kc * 32 + g * 8];
                blf[ni] = *(const bf16x8*)&Bl[row * 64 + kc * 32 + g * 8];
            }
            #pragma unroll
            for (int mi = 0; mi < 4; ++mi) {
                const int row = wm * 64 + mi * 16 + lq;
                const bf16x8 ahf = *(const bf16x8*)&Ah[row * 64 + kc * 32 + g * 8];
                const bf16x8 alf = *(const bf16x8*)&Al[row * 64 + kc * 32 + g * 8];
                #pragma unroll
                for (int ni = 0; ni < 4; ++ni) {
                    acc[mi][ni] = __builtin_amdgcn_mfma_f32_16x16x32_bf16(ahf, bhf[ni], acc[mi][ni], 0, 0, 0);
                    acc[mi][ni] = __builtin_amdgcn_mfma_f32_16x16x32_bf16(alf, bhf[ni], acc[mi][ni], 0, 0, 0);
                    acc[mi][ni] = __builtin_amdgcn_mfma_f32_16x16x32_bf16(ahf, blf[ni], acc[mi][ni], 0, 0, 0);
                }
            }
        }
        __syncthreads();
    }

    // epilogue: D row = m = wm*64+mi*16+g*4+r ; col = n = wn*64+ni*16+lq
    const int which = n0 >> 10;                 // 0=Q,1=K,2=V (128 | 1024)
    const int nn0 = n0 & 1023;
    const int b = m0 >> 11;
    const int tb = (m0 & 2047) + wm * 64;
    if (which < 2) {
        ushort* out = which ? Kh : Qh;
        #pragma unroll
        for (int mi = 0; mi < 4; ++mi) {
            const int t = tb + mi * 16 + g * 4;
            #pragma unroll
            for (int ni = 0; ni < 4; ++ni) {
                const int n = nn0 + wn * 64 + ni * 16 + lq;
                const int h = n >> 6, d = n & 63;
                ushort* op = out + ((size_t)(b * NH + h) * T_DIM + t) * HD + d;
                #pragma unroll
                for (int r = 0; r < 4; ++r) op[r * HD] = f2bf(acc[mi][ni][r]);
            }
        }
    } else {
        #pragma unroll
        for (int mi = 0; mi < 4; ++mi) {
            const int t = tb + mi * 16 + g * 4;
            #pragma unroll
            for (int ni = 0; ni < 4; ++ni) {
                const int n = nn0 + wn * 64 + ni * 16 + lq;
                const int h = n >> 6, d = n & 63;
                ushort4 v;
                v.x = f2bf(acc[mi][ni][0]); v.y = f2bf(acc[mi][ni][1]);
                v.z = f2bf(acc[mi][ni][2]); v.w = f2bf(acc[mi][ni][3]);
                *(ushort4*)(Vt + ((size_t)(b * NH + h) * HD + d) * T_DIM + t) = v;
            }
        }
    }
}

// ---------------------------------------------------------------------------
// Kernel 2: causal flash attention, bf16 MFMA (16x16x32) — unchanged from R5
// except the epilogue now stores O as bf16 hi/lo pair (fp32-equivalent).
// ---------------------------------------------------------------------------
__global__ __launch_bounds__(256, 2) void attn_kernel(
    const ushort* __restrict__ Qh,
    const ushort* __restrict__ Kh,
    const ushort* __restrict__ Vt,
    ushort* __restrict__ Ohh,
    ushort* __restrict__ Ohl)
{
    __shared__ float olds[4][16][68];

    const int tid  = threadIdx.x;
    const int wave = tid >> 6, lane = tid & 63;
    const int lq   = lane & 15, g = lane >> 4;
    const int bh   = blockIdx.y;
    const int qt   = (T_DIM / 64 - 1) - blockIdx.x;   // heavy-first
    const int qw0  = qt * 64 + wave * 16;
    const int q    = qw0 + lq;
    const int ntiles = qt + 1;

    const ushort* Qb = Qh + ((size_t)bh * T_DIM + qw0 + lq) * HD;
    bf16x8 qf[2];
    qf[0] = *(const bf16x8*)(Qb + g * 8);
    qf[1] = *(const bf16x8*)(Qb + 32 + g * 8);

    const ushort* Kb = Kh + (size_t)bh * T_DIM * HD;
    const ushort* Vb = Vt + (size_t)bh * HD * T_DIM;

    f32x4 o[4];
    #pragma unroll
    for (int dt = 0; dt < 4; ++dt) { o[dt][0]=0.f; o[dt][1]=0.f; o[dt][2]=0.f; o[dt][3]=0.f; }
    float m = -3.0e38f, l = 0.f;

    for (int kvt = 0; kvt < ntiles; ++kvt) {
        const bool lastt = (kvt == ntiles - 1);

        bf16x8 kf[4][2];
        const ushort* Kt = Kb + (size_t)(kvt * 64) * HD;
        #pragma unroll
        for (int kt = 0; kt < 4; ++kt) {
            const ushort* kr = Kt + (size_t)(kt * 16 + lq) * HD + g * 8;
            kf[kt][0] = *(const bf16x8*)(kr);
            kf[kt][1] = *(const bf16x8*)(kr + 32);
        }

        bf16x8 vf[4][2];
        #pragma unroll
        for (int dt = 0; dt < 4; ++dt) {
            const ushort* vr = Vb + (size_t)(dt * 16 + lq) * T_DIM + kvt * 64 + g * 4;
            #pragma unroll
            for (int cc = 0; cc < 2; ++cc) {
                ushort4 lo = *(const ushort4*)(vr + cc * 32);
                ushort4 hi = *(const ushort4*)(vr + cc * 32 + 16);
                bf16x8 v;
                v[0] = (short)lo.x; v[1] = (short)lo.y; v[2] = (short)lo.z; v[3] = (short)lo.w;
                v[4] = (short)hi.x; v[5] = (short)hi.y; v[6] = (short)hi.z; v[7] = (short)hi.w;
                vf[dt][cc] = v;
            }
        }

        f32x4 s[4];
        #pragma unroll
        for (int kt = 0; kt < 4; ++kt) {
            f32x4 z; z[0]=0.f; z[1]=0.f; z[2]=0.f; z[3]=0.f;
            z = __builtin_amdgcn_mfma_f32_16x16x32_bf16(kf[kt][0], qf[0], z, 0, 0, 0);
            s[kt] = __builtin_amdgcn_mfma_f32_16x16x32_bf16(kf[kt][1], qf[1], z, 0, 0, 0);
        }

        float p[4][4];
        float pmax = -3.0e38f;
        #pragma unroll
        for (int kt = 0; kt < 4; ++kt) {
            #pragma unroll
            for (int r = 0; r < 4; ++r) {
                float v = s[kt][r] * 0.125f;
                if (lastt) {
                    const int kv = kvt * 64 + kt * 16 + g * 4 + r;
                    if (kv > q) v = -3.0e38f;
                }
                p[kt][r] = v;
                pmax = fmaxf(pmax, v);
            }
        }
        pmax = fmaxf(pmax, __shfl_xor(pmax, 16));
        pmax = fmaxf(pmax, __shfl_xor(pmax, 32));
        const float mnew = fmaxf(m, pmax);
        const float cf = __expf(m - mnew);
        m = mnew;

        float rs = 0.f;
        #pragma unroll
        for (int kt = 0; kt < 4; ++kt) {
            #pragma unroll
            for (int r = 0; r < 4; ++r) {
                const float w = __expf(p[kt][r] - mnew);
                p[kt][r] = w;
                rs += w;
            }
        }
        rs += __shfl_xor(rs, 16);
        rs += __shfl_xor(rs, 32);
        l = l * cf + rs;

        #pragma unroll
        for (int dt = 0; dt < 4; ++dt) {
            o[dt][0] *= cf; o[dt][1] *= cf; o[dt][2] *= cf; o[dt][3] *= cf;
        }

        bf16x8 pf[2];
        #pragma unroll
        for (int cc = 0; cc < 2; ++cc) {
            #pragma unroll
            for (int j = 0; j < 8; ++j)
                pf[cc][j] = (short)f2bf(p[cc * 2 + (j >> 2)][j & 3]);
        }

        #pragma unroll
        for (int dt = 0; dt < 4; ++dt) {
            o[dt] = __builtin_amdgcn_mfma_f32_16x16x32_bf16(vf[dt][0], pf[0], o[dt], 0, 0, 0);
            o[dt] = __builtin_amdgcn_mfma_f32_16x16x32_bf16(vf[dt][1], pf[1], o[dt], 0, 0, 0);
        }
    }

    const float invl = 1.0f / l;
    #pragma unroll
    for (int dt = 0; dt < 4; ++dt) {
        #pragma unroll
        for (int r = 0; r < 4; ++r)
            olds[wave][lq][dt * 16 + g * 4 + r] = o[dt][r] * invl;
    }
    #pragma unroll
    for (int pp = 0; pp < 4; ++pp) {
        const int qq = pp * 4 + g;
        const float4 v4 = *(const float4*)&olds[wave][qq][lq * 4];
        ushort4 hv, lv;
        hv.x = f2bf(v4.x); lv.x = f2bf(v4.x - bf2f(hv.x));
        hv.y = f2bf(v4.y); lv.y = f2bf(v4.y - bf2f(hv.y));
        hv.z = f2bf(v4.z); lv.z = f2bf(v4.z - bf2f(hv.z));
        hv.w = f2bf(v4.w); lv.w = f2bf(v4.w - bf2f(hv.w));
        const size_t off = ((size_t)bh * T_DIM + qw0 + qq) * HD + lq * 4;
        *(ushort4*)(Ohh + off) = hv;
        *(ushort4*)(Ohl + off) = lv;
    }
}

// ---------------------------------------------------------------------------
// Kernel 3: output projection, bf16 MFMA split. A = Oh hi/lo (head-major),
// B = WcT hi/lo. out fp32 + bias.
// ---------------------------------------------------------------------------
__global__ __launch_bounds__(256, 2) void out_mfma(
    const ushort* __restrict__ Ahh, const ushort* __restrict__ Ahl,
    const ushort* __restrict__ BTh, const ushort* __restrict__ BTl,
    const float* __restrict__ bc, float* __restrict__ out)
{
    __shared__ ushort Ah[128 * 64], Al[128 * 64], Bh[128 * 64], Bl[128 * 64];

    const int tid = threadIdx.x;
    const int wave = tid >> 6, lane = tid & 63, lq = lane & 15, g = lane >> 4;
    const int m0 = blockIdx.x * 128;
    const int n0 = blockIdx.y * 128;
    const int wm = wave >> 1, wn = wave & 1;
    const int sm = tid >> 3;
    const int sk = (tid & 7) * 8;
    const int b = m0 >> 11, t0 = m0 & 2047;

    f32x4 acc[4][4];
    #pragma unroll
    for (int i = 0; i < 4; ++i)
        #pragma unroll
        for (int j = 0; j < 4; ++j) { acc[i][j][0]=0.f; acc[i][j][1]=0.f; acc[i][j][2]=0.f; acc[i][j][3]=0.f; }

    for (int kt = 0; kt < 16; ++kt) {
        // A tile: head kt of Oh, rows t0..t0+127, contiguous [128][64]
        const size_t abase = ((size_t)(b * NH + kt) * T_DIM + t0) * HD;
        #pragma unroll
        for (int rd = 0; rd < 4; ++rd) {
            const int mm = sm + rd * 32;
            const int lo = rd * 2048 + wave * 512;
            gload16(Ahh + abase + (size_t)mm * HD + sk, &Ah[lo]);
            gload16(Ahl + abase + (size_t)mm * HD + sk, &Al[lo]);
            gload16(BTh + (size_t)(n0 + mm) * 1024 + kt * 64 + sk, &Bh[lo]);
            gload16(BTl + (size_t)(n0 + mm) * 1024 + kt * 64 + sk, &Bl[lo]);
        }
        __syncthreads();

        #pragma unroll
        for (int kc = 0; kc < 2; ++kc) {
            bf16x8 bhf[4], blf[4];
            #pragma unroll
            for (int ni = 0; ni < 4; ++ni) {
                const int row = wn * 64 + ni * 16 + lq;
                bhf[ni] = *(const bf16x8*)&Bh[row * 64 + kc * 32 + g * 8];
                blf[ni] = *(const bf16x8*)&Bl[row * 64 + kc * 32 + g * 8];
            }
            #pragma unroll
            for (int mi = 0; mi < 4; ++mi) {
                const int row = wm * 64 + mi * 16 + lq;
                const bf16x8 ahf = *(const bf16x8*)&Ah[row * 64 + kc * 32 + g * 8];
                const bf16x8 alf = *(const bf16x8*)&Al[row * 64 + kc * 32 + g * 8];
                #pragma unroll
                for (int ni = 0; ni < 4; ++ni) {
                    acc[mi][ni] = __builtin_amdgcn_mfma_f32_16x16x32_bf16(ahf, bhf[ni], acc[mi][ni], 0, 0, 0);
                    acc[mi][ni] = __builtin_amdgcn_mfma_f32_16x16x32_bf16(alf, bhf[ni], acc[mi][ni], 0, 0, 0);
                    acc[mi][ni] = __builtin_amdgcn_mfma_f32_16x16x32_bf16(ahf, blf[ni], acc[mi][ni], 0, 0, 0);
                }
            }
        }
        __syncthreads();
    }

    #pragma unroll
    for (int ni = 0; ni < 4; ++ni) {
        const int n = n0 + wn * 64 + ni * 16 + lq;
        const float bias = bc[n];
        #pragma unroll
        for (int mi = 0; mi < 4; ++mi) {
            const int mrow = m0 + wm * 64 + mi * 16 + g * 4;
            #pragma unroll
            for (int r = 0; r < 4; ++r)
                out[(size_t)(mrow + r) * C_DIM + n] = acc[mi][ni][r] + bias;
        }
    }
}

// ---------------------------------------------------------------------------
extern "C" void kernel_launch(void* const* d_in, const int* in_sizes, int n_in,
                              void* d_out, int out_size, void* d_ws, size_t ws_size,
                              hipStream_t stream)
{
    const float* x  = (const float*)d_in[0];
    const float* Wq = (const float*)d_in[1];
    const float* Wk = (const float*)d_in[2];
    const float* Wv = (const float*)d_in[3];
    const float* Wc = (const float*)d_in[4];
    const float* bc = (const float*)d_in[5];
    float* out = (float*)d_out;

    const size_t PL   = (size_t)M_TOT * C_DIM;   // 8,388,608
    const size_t WQKV = (size_t)3072 * 1024;     // 3,145,728
    const size_t WC   = (size_t)1024 * 1024;     // 1,048,576

    ushort* ws   = (ushort*)d_ws;
    ushort* xh   = ws;
    ushort* xl   = xh + PL;
    ushort* WTh  = xl + PL;
    ushort* WTl  = WTh + WQKV;
    ushort* WcTh = WTl + WQKV;
    ushort* WcTl = WcTh + WC;
    ushort* Qh   = WcTl + WC;
    ushort* Kh   = Qh + PL;
    ushort* Vt   = Kh + PL;
    ushort* Ohh  = Vt + PL;
    ushort* Ohl  = Ohh + PL;

    decomp_x<<<4096, 256, 0, stream>>>(x, xh, xl);
    wtrans<<<dim3(16, 16, 4), 256, 0, stream>>>(Wq, Wk, Wv, Wc, WTh, WTl, WcTh, WcTl);
    qkv_mfma<<<dim3(M_TOT / 128, 24), 256, 0, stream>>>(xh, xl, WTh, WTl, Qh, Kh, Vt);
    attn_kernel<<<dim3(T_DIM / 64, BHT), 256, 0, stream>>>(Qh, Kh, Vt, Ohh, Ohl);
    out_mfma<<<dim3(M_TOT / 128, C_DIM / 128), 256, 0, stream>>>(Ohh, Ohl, WcTh, WcTl, bc, out);
}

// Round 8
// 430.477 us; speedup vs baseline: 8.9270x; 2.1835x over previous
//
#include <hip/hip_runtime.h>
#include <hip/hip_bf16.h>
#include <math.h>

// B=4, T=2048, C=1024, H=16, HD=64, M = B*T = 8192
// ws (ushort units, 128 MiB total):
//   xh,xl [8192][1024] | WTh,WTl [3072][1024] | WcTh,WcTl [1024][1024]
//   Qh,Kh [64][2048][64] | Vt [64][64][2048] | Ohh,Ohl [64][2048][64]

#define M_TOT   8192
#define C_DIM   1024
#define T_DIM   2048
#define NH      16
#define HD      64
#define BHT     (NH * 4)        // B*H = 64

typedef short  bf16x8 __attribute__((ext_vector_type(8)));
typedef ushort u16x8  __attribute__((ext_vector_type(8)));
typedef float  f32x4  __attribute__((ext_vector_type(4)));

static __device__ __forceinline__ ushort f2bf(float f) {
    union { __hip_bfloat16 h; ushort u; } cv;
    cv.h = __float2bfloat16(f);
    return cv.u;
}
static __device__ __forceinline__ float bf2f(ushort u) {
    union { ushort u; __hip_bfloat16 h; } cv;
    cv.u = u;
    return __bfloat162float(cv.h);
}
static __device__ __forceinline__ void gload16(const ushort* g, ushort* l) {
    __builtin_amdgcn_global_load_lds(
        (const __attribute__((address_space(1))) void*)g,
        (__attribute__((address_space(3))) void*)l, 16, 0, 0);
}

// ---------------------------------------------------------------------------
// Decomp 1: x fp32 -> xh/xl bf16 (hi/lo split). 8 elems/thread.
// ---------------------------------------------------------------------------
__global__ __launch_bounds__(256) void decomp_x(
    const float* __restrict__ x, ushort* __restrict__ xh, ushort* __restrict__ xl)
{
    const int i = blockIdx.x * 256 + threadIdx.x;
    const float4 a = ((const float4*)x)[2 * i];
    const float4 b = ((const float4*)x)[2 * i + 1];
    const float v[8] = {a.x, a.y, a.z, a.w, b.x, b.y, b.z, b.w};
    u16x8 h, l;
    #pragma unroll
    for (int e = 0; e < 8; ++e) {
        h[e] = f2bf(v[e]);
        l[e] = f2bf(v[e] - bf2f(h[e]));
    }
    ((u16x8*)xh)[i] = h;
    ((u16x8*)xl)[i] = l;
}

// ---------------------------------------------------------------------------
// Decomp 2: transpose W (fp32 [1024][1024]) -> WT hi/lo bf16 [n][k].
// ---------------------------------------------------------------------------
__global__ __launch_bounds__(256) void wtrans(
    const float* __restrict__ Wq, const float* __restrict__ Wk,
    const float* __restrict__ Wv, const float* __restrict__ Wc,
    ushort* __restrict__ WTh, ushort* __restrict__ WTl,
    ushort* __restrict__ WcTh, ushort* __restrict__ WcTl)
{
    __shared__ float tile[64][65];
    const int z = blockIdx.z;
    const float* W = (z == 0) ? Wq : (z == 1) ? Wk : (z == 2) ? Wv : Wc;
    const int n0 = blockIdx.x * 64, k0 = blockIdx.y * 64;
    const int tid = threadIdx.x;

    #pragma unroll
    for (int i = 0; i < 4; ++i) {
        const int lin = i * 1024 + tid * 4;
        const int r = lin >> 6, c = lin & 63;
        const float4 v = *(const float4*)(W + (size_t)(k0 + r) * 1024 + n0 + c);
        tile[r][c] = v.x; tile[r][c + 1] = v.y; tile[r][c + 2] = v.z; tile[r][c + 3] = v.w;
    }
    __syncthreads();

    ushort* oh = (z < 3) ? WTh : WcTh;
    ushort* ol = (z < 3) ? WTl : WcTl;
    const size_t rowbase = (z < 3) ? (size_t)z * 1024 : 0;
    #pragma unroll
    for (int i = 0; i < 4; ++i) {
        const int lin = i * 1024 + tid * 4;
        const int rn = lin >> 6, ck = lin & 63;
        ushort4 hv, lv;
        float v0 = tile[ck + 0][rn], v1 = tile[ck + 1][rn];
        float v2 = tile[ck + 2][rn], v3 = tile[ck + 3][rn];
        hv.x = f2bf(v0); lv.x = f2bf(v0 - bf2f(hv.x));
        hv.y = f2bf(v1); lv.y = f2bf(v1 - bf2f(hv.y));
        hv.z = f2bf(v2); lv.z = f2bf(v2 - bf2f(hv.z));
        hv.w = f2bf(v3); lv.w = f2bf(v3 - bf2f(hv.w));
        const size_t off = (rowbase + n0 + rn) * 1024 + k0 + ck;
        *(ushort4*)(oh + off) = hv;
        *(ushort4*)(ol + off) = lv;
    }
}

// ---------------------------------------------------------------------------
// Kernel 1: QKV projection, bf16 MFMA, split-bf16 (AhBh + AlBh + AhBl).
// (unchanged from R7 — verified at 940us total)
// ---------------------------------------------------------------------------
__global__ __launch_bounds__(256, 2) void qkv_mfma(
    const ushort* __restrict__ xh, const ushort* __restrict__ xl,
    const ushort* __restrict__ WTh, const ushort* __restrict__ WTl,
    ushort* __restrict__ Qh, ushort* __restrict__ Kh, ushort* __restrict__ Vt)
{
    __shared__ ushort Ah[128 * 64], Al[128 * 64], Bh[128 * 64], Bl[128 * 64]; // 64 KB

    const int tid = threadIdx.x;
    const int wave = tid >> 6, lane = tid & 63, lq = lane & 15, g = lane >> 4;
    const int m0 = blockIdx.x * 128;
    const int n0 = blockIdx.y * 128;
    const int wm = wave >> 1, wn = wave & 1;
    const int sm = tid >> 3;
    const int sk = (tid & 7) * 8;

    f32x4 acc[4][4];
    #pragma unroll
    for (int i = 0; i < 4; ++i)
        #pragma unroll
        for (int j = 0; j < 4; ++j) { acc[i][j][0]=0.f; acc[i][j][1]=0.f; acc[i][j][2]=0.f; acc[i][j][3]=0.f; }

    for (int kt = 0; kt < 16; ++kt) {
        const int ko = kt * 64 + sk;
        #pragma unroll
        for (int rd = 0; rd < 4; ++rd) {
            const int mm = sm + rd * 32;
            const int lo = rd * 2048 + wave * 512;
            gload16(xh  + (size_t)(m0 + mm) * 1024 + ko, &Ah[lo]);
            gload16(xl  + (size_t)(m0 + mm) * 1024 + ko, &Al[lo]);
            gload16(WTh + (size_t)(n0 + mm) * 1024 + ko, &Bh[lo]);
            gload16(WTl + (size_t)(n0 + mm) * 1024 + ko, &Bl[lo]);
        }
        __syncthreads();

        #pragma unroll
        for (int kc = 0; kc < 2; ++kc) {
            bf16x8 bhf[4], blf[4];
            #pragma unroll
            for (int ni = 0; ni < 4; ++ni) {
                const int row = wn * 64 + ni * 16 + lq;
                bhf[ni] = *(const bf16x8*)&Bh[row * 64 + kc * 32 + g * 8];
                blf[ni] = *(const bf16x8*)&Bl[row * 64 + kc * 32 + g * 8];
            }
            #pragma unroll
            for (int mi = 0; mi < 4; ++mi) {
                const int row = wm * 64 + mi * 16 + lq;
                const bf16x8 ahf = *(const bf16x8*)&Ah[row * 64 + kc * 32 + g * 8];
                const bf16x8 alf = *(const bf16x8*)&Al[row * 64 + kc * 32 + g * 8];
                #pragma unroll
                for (int ni = 0; ni < 4; ++ni) {
                    acc[mi][ni] = __builtin_amdgcn_mfma_f32_16x16x32_bf16(ahf, bhf[ni], acc[mi][ni], 0, 0, 0);
                    acc[mi][ni] = __builtin_amdgcn_mfma_f32_16x16x32_bf16(alf, bhf[ni], acc[mi][ni], 0, 0, 0);
                    acc[mi][ni] = __builtin_amdgcn_mfma_f32_16x16x32_bf16(ahf, blf[ni], acc[mi][ni], 0, 0, 0);
                }
            }
        }
        __syncthreads();
    }

    const int which = n0 >> 10;
    const int nn0 = n0 & 1023;
    const int b = m0 >> 11;
    const int tb = (m0 & 2047) + wm * 64;
    if (which < 2) {
        ushort* out = which ? Kh : Qh;
        #pragma unroll
        for (int mi = 0; mi < 4; ++mi) {
            const int t = tb + mi * 16 + g * 4;
            #pragma unroll
            for (int ni = 0; ni < 4; ++ni) {
                const int n = nn0 + wn * 64 + ni * 16 + lq;
                const int h = n >> 6, d = n & 63;
                ushort* op = out + ((size_t)(b * NH + h) * T_DIM + t) * HD + d;
                #pragma unroll
                for (int r = 0; r < 4; ++r) op[r * HD] = f2bf(acc[mi][ni][r]);
            }
        }
    } else {
        #pragma unroll
        for (int mi = 0; mi < 4; ++mi) {
            const int t = tb + mi * 16 + g * 4;
            #pragma unroll
            for (int ni = 0; ni < 4; ++ni) {
                const int n = nn0 + wn * 64 + ni * 16 + lq;
                const int h = n >> 6, d = n & 63;
                ushort4 v;
                v.x = f2bf(acc[mi][ni][0]); v.y = f2bf(acc[mi][ni][1]);
                v.z = f2bf(acc[mi][ni][2]); v.w = f2bf(acc[mi][ni][3]);
                *(ushort4*)(Vt + ((size_t)(b * NH + h) * HD + d) * T_DIM + t) = v;
            }
        }
    }
}

// ---------------------------------------------------------------------------
// Kernel 2: causal flash attention, bf16 MFMA, LDS-staged K/V.
// NEW vs R7: K(8KB)+V(8KB) tiles staged once per block via global_load_lds
// (kills the 4x redundant per-wave global loads seen in FETCH_SIZE),
// double-buffered 2-phase pipeline (prefetch tile k+1 during compute of k),
// rule-21 XOR swizzle (byte ^= (row&7)<<4; inverse-swizzled global source,
// swizzled reads) to kill the 16-way bank conflict on fragment reads.
// Compute pipeline (swapped-QK^T softmax, PV mapping) unchanged.
// ---------------------------------------------------------------------------
__global__ __launch_bounds__(256, 2) void attn_kernel(
    const ushort* __restrict__ Qh,
    const ushort* __restrict__ Kh,
    const ushort* __restrict__ Vt,
    ushort* __restrict__ Ohh,
    ushort* __restrict__ Ohl)
{
    __shared__ __align__(16) ushort sbuf[2][8192];   // [buf]: K 0..4095 | V 4096..8191 (32 KB)

    const int tid  = threadIdx.x;
    const int wave = tid >> 6, lane = tid & 63;
    const int lq   = lane & 15, g = lane >> 4;
    const int bh   = blockIdx.y;
    const int qt   = (T_DIM / 64 - 1) - blockIdx.x;   // heavy-first
    const int qw0  = qt * 64 + wave * 16;
    const int q    = qw0 + lq;
    const int ntiles = qt + 1;

    const ushort* Qb = Qh + ((size_t)bh * T_DIM + q) * HD;
    bf16x8 qf[2];
    qf[0] = *(const bf16x8*)(Qb + g * 8);
    qf[1] = *(const bf16x8*)(Qb + 32 + g * 8);

    const ushort* Kb = Kh + (size_t)bh * T_DIM * HD;
    const ushort* Vb = Vt + (size_t)bh * HD * T_DIM;

    // staging: thread covers row = rr*32 + (tid>>3), 16B unit = tid&7.
    // source unit pre-swizzled (unit ^ row&7) so linear LDS + swizzled reads agree.
    const int srow  = tid >> 3;
    const int sunit = tid & 7;

    f32x4 o[4];
    #pragma unroll
    for (int dt = 0; dt < 4; ++dt) { o[dt][0]=0.f; o[dt][1]=0.f; o[dt][2]=0.f; o[dt][3]=0.f; }
    float m = -3.0e38f, l = 0.f;

    // prologue: stage tile 0 into buf 0
    {
        #pragma unroll
        for (int rr = 0; rr < 2; ++rr) {
            const int row = rr * 32 + srow;
            const int un  = sunit ^ (row & 7);
            gload16(Kb + (size_t)row * HD + un * 8,    &sbuf[0][rr * 2048 + wave * 512]);
            gload16(Vb + (size_t)row * T_DIM + un * 8, &sbuf[0][4096 + rr * 2048 + wave * 512]);
        }
    }
    __syncthreads();

    int cur = 0;
    for (int kvt = 0; kvt < ntiles; ++kvt) {
        const bool lastt = (kvt == ntiles - 1);

        // prefetch next tile into the other buffer (in flight during compute)
        if (!lastt) {
            const ushort* Kt  = Kb + (size_t)(kvt + 1) * 64 * HD;
            const ushort* Vtt = Vb + (kvt + 1) * 64;
            const int nb = cur ^ 1;
            #pragma unroll
            for (int rr = 0; rr < 2; ++rr) {
                const int row = rr * 32 + srow;
                const int un  = sunit ^ (row & 7);
                gload16(Kt + (size_t)row * HD + un * 8,    &sbuf[nb][rr * 2048 + wave * 512]);
                gload16(Vtt + (size_t)row * T_DIM + un * 8, &sbuf[nb][4096 + rr * 2048 + wave * 512]);
            }
        }

        const char* Ksb = (const char*)&sbuf[cur][0];
        const char* Vsb = (const char*)&sbuf[cur][4096];
        const int rxor = (lq & 7) << 4;

        // K fragments from LDS (swizzled): logical row kt*16+lq, byte col c*64+g*16
        bf16x8 kf[4][2];
        #pragma unroll
        for (int kt = 0; kt < 4; ++kt) {
            const int rb = (kt * 16 + lq) * 128;
            kf[kt][0] = *(const bf16x8*)(Ksb + rb + ((g * 16) ^ rxor));
            kf[kt][1] = *(const bf16x8*)(Ksb + rb + ((64 + g * 16) ^ rxor));
        }
        // V fragments from LDS (swizzled): logical row dt*16+lq, byte cols cc*64+g*8, +32
        bf16x8 vf[4][2];
        #pragma unroll
        for (int dt = 0; dt < 4; ++dt) {
            const int rb = (dt * 16 + lq) * 128;
            #pragma unroll
            for (int cc = 0; cc < 2; ++cc) {
                ushort4 lo = *(const ushort4*)(Vsb + rb + ((cc * 64 + g * 8) ^ rxor));
                ushort4 hi = *(const ushort4*)(Vsb + rb + ((cc * 64 + g * 8 + 32) ^ rxor));
                bf16x8 v;
                v[0] = (short)lo.x; v[1] = (short)lo.y; v[2] = (short)lo.z; v[3] = (short)lo.w;
                v[4] = (short)hi.x; v[5] = (short)hi.y; v[6] = (short)hi.z; v[7] = (short)hi.w;
                vf[dt][cc] = v;
            }
        }

        // S^T = K · Q^T
        __builtin_amdgcn_s_setprio(1);
        f32x4 s[4];
        #pragma unroll
        for (int kt = 0; kt < 4; ++kt) {
            f32x4 z; z[0]=0.f; z[1]=0.f; z[2]=0.f; z[3]=0.f;
            z = __builtin_amdgcn_mfma_f32_16x16x32_bf16(kf[kt][0], qf[0], z, 0, 0, 0);
            s[kt] = __builtin_amdgcn_mfma_f32_16x16x32_bf16(kf[kt][1], qf[1], s[kt] = z, 0, 0, 0);
        }
        __builtin_amdgcn_s_setprio(0);

        // online softmax (lane-local: q = lane&15)
        float p[4][4];
        float pmax = -3.0e38f;
        #pragma unroll
        for (int kt = 0; kt < 4; ++kt) {
            #pragma unroll
            for (int r = 0; r < 4; ++r) {
                float v = s[kt][r] * 0.125f;
                if (lastt) {
                    const int kv = kvt * 64 + kt * 16 + g * 4 + r;
                    if (kv > q) v = -3.0e38f;
                }
                p[kt][r] = v;
                pmax = fmaxf(pmax, v);
            }
        }
        pmax = fmaxf(pmax, __shfl_xor(pmax, 16));
        pmax = fmaxf(pmax, __shfl_xor(pmax, 32));
        const float mnew = fmaxf(m, pmax);
        const float cf = __expf(m - mnew);
        m = mnew;

        float rs = 0.f;
        #pragma unroll
        for (int kt = 0; kt < 4; ++kt) {
            #pragma unroll
            for (int r = 0; r < 4; ++r) {
                const float w = __expf(p[kt][r] - mnew);
                p[kt][r] = w;
                rs += w;
            }
        }
        rs += __shfl_xor(rs, 16);
        rs += __shfl_xor(rs, 32);
        l = l * cf + rs;

        #pragma unroll
        for (int dt = 0; dt < 4; ++dt) {
            o[dt][0] *= cf; o[dt][1] *= cf; o[dt][2] *= cf; o[dt][3] *= cf;
        }

        // pack P^T (same k-mapping as vf)
        bf16x8 pf[2];
        #pragma unroll
        for (int cc = 0; cc < 2; ++cc) {
            #pragma unroll
            for (int j = 0; j < 8; ++j)
                pf[cc][j] = (short)f2bf(p[cc * 2 + (j >> 2)][j & 3]);
        }

        // O^T += V^T · P^T
        __builtin_amdgcn_s_setprio(1);
        #pragma unroll
        for (int dt = 0; dt < 4; ++dt) {
            o[dt] = __builtin_amdgcn_mfma_f32_16x16x32_bf16(vf[dt][0], pf[0], o[dt], 0, 0, 0);
            o[dt] = __builtin_amdgcn_mfma_f32_16x16x32_bf16(vf[dt][1], pf[1], o[dt], 0, 0, 0);
        }
        __builtin_amdgcn_s_setprio(0);

        // drain prefetch + release current buffer (2-phase: one barrier per tile)
        __syncthreads();
        cur ^= 1;
    }

    // epilogue: divide by l, transpose via LDS (reuse staging buffer), bf16 hi/lo out
    float* olds = (float*)&sbuf[0][0];   // [4][16][68] floats = 17408 B <= 32 KB
    const float invl = 1.0f / l;
    #pragma unroll
    for (int dt = 0; dt < 4; ++dt) {
        #pragma unroll
        for (int r = 0; r < 4; ++r)
            olds[wave * 1088 + lq * 68 + dt * 16 + g * 4 + r] = o[dt][r] * invl;
    }
    #pragma unroll
    for (int pp = 0; pp < 4; ++pp) {
        const int qq = pp * 4 + g;
        const float4 v4 = *(const float4*)&olds[wave * 1088 + qq * 68 + lq * 4];
        ushort4 hv, lv;
        hv.x = f2bf(v4.x); lv.x = f2bf(v4.x - bf2f(hv.x));
        hv.y = f2bf(v4.y); lv.y = f2bf(v4.y - bf2f(hv.y));
        hv.z = f2bf(v4.z); lv.z = f2bf(v4.z - bf2f(hv.z));
        hv.w = f2bf(v4.w); lv.w = f2bf(v4.w - bf2f(hv.w));
        const size_t off = ((size_t)bh * T_DIM + qw0 + qq) * HD + lq * 4;
        *(ushort4*)(Ohh + off) = hv;
        *(ushort4*)(Ohl + off) = lv;
    }
}

// ---------------------------------------------------------------------------
// Kernel 3: output projection, bf16 MFMA split (unchanged from R7).
// ---------------------------------------------------------------------------
__global__ __launch_bounds__(256, 2) void out_mfma(
    const ushort* __restrict__ Ahh, const ushort* __restrict__ Ahl,
    const ushort* __restrict__ BTh, const ushort* __restrict__ BTl,
    const float* __restrict__ bc, float* __restrict__ out)
{
    __shared__ ushort Ah[128 * 64], Al[128 * 64], Bh[128 * 64], Bl[128 * 64];

    const int tid = threadIdx.x;
    const int wave = tid >> 6, lane = tid & 63, lq = lane & 15, g = lane >> 4;
    const int m0 = blockIdx.x * 128;
    const int n0 = blockIdx.y * 128;
    const int wm = wave >> 1, wn = wave & 1;
    const int sm = tid >> 3;
    const int sk = (tid & 7) * 8;
    const int b = m0 >> 11, t0 = m0 & 2047;

    f32x4 acc[4][4];
    #pragma unroll
    for (int i = 0; i < 4; ++i)
        #pragma unroll
        for (int j = 0; j < 4; ++j) { acc[i][j][0]=0.f; acc[i][j][1]=0.f; acc[i][j][2]=0.f; acc[i][j][3]=0.f; }

    for (int kt = 0; kt < 16; ++kt) {
        const size_t abase = ((size_t)(b * NH + kt) * T_DIM + t0) * HD;
        #pragma unroll
        for (int rd = 0; rd < 4; ++rd) {
            const int mm = sm + rd * 32;
            const int lo = rd * 2048 + wave * 512;
            gload16(Ahh + abase + (size_t)mm * HD + sk, &Ah[lo]);
            gload16(Ahl + abase + (size_t)mm * HD + sk, &Al[lo]);
            gload16(BTh + (size_t)(n0 + mm) * 1024 + kt * 64 + sk, &Bh[lo]);
            gload16(BTl + (size_t)(n0 + mm) * 1024 + kt * 64 + sk, &Bl[lo]);
        }
        __syncthreads();

        #pragma unroll
        for (int kc = 0; kc < 2; ++kc) {
            bf16x8 bhf[4], blf[4];
            #pragma unroll
            for (int ni = 0; ni < 4; ++ni) {
                const int row = wn * 64 + ni * 16 + lq;
                bhf[ni] = *(const bf16x8*)&Bh[row * 64 + kc * 32 + g * 8];
                blf[ni] = *(const bf16x8*)&Bl[row * 64 + kc * 32 + g * 8];
            }
            #pragma unroll
            for (int mi = 0; mi < 4; ++mi) {
                const int row = wm * 64 + mi * 16 + lq;
                const bf16x8 ahf = *(const bf16x8*)&Ah[row * 64 + kc * 32 + g * 8];
                const bf16x8 alf = *(const bf16x8*)&Al[row * 64 + kc * 32 + g * 8];
                #pragma unroll
                for (int ni = 0; ni < 4; ++ni) {
                    acc[mi][ni] = __builtin_amdgcn_mfma_f32_16x16x32_bf16(ahf, bhf[ni], acc[mi][ni], 0, 0, 0);
                    acc[mi][ni] = __builtin_amdgcn_mfma_f32_16x16x32_bf16(alf, bhf[ni], acc[mi][ni], 0, 0, 0);
                    acc[mi][ni] = __builtin_amdgcn_mfma_f32_16x16x32_bf16(ahf, blf[ni], acc[mi][ni], 0, 0, 0);
                }
            }
        }
        __syncthreads();
    }

    #pragma unroll
    for (int ni = 0; ni < 4; ++ni) {
        const int n = n0 + wn * 64 + ni * 16 + lq;
        const float bias = bc[n];
        #pragma unroll
        for (int mi = 0; mi < 4; ++mi) {
            const int mrow = m0 + wm * 64 + mi * 16 + g * 4;
            #pragma unroll
            for (int r = 0; r < 4; ++r)
                out[(size_t)(mrow + r) * C_DIM + n] = acc[mi][ni][r] + bias;
        }
    }
}

// ---------------------------------------------------------------------------
extern "C" void kernel_launch(void* const* d_in, const int* in_sizes, int n_in,
                              void* d_out, int out_size, void* d_ws, size_t ws_size,
                              hipStream_t stream)
{
    const float* x  = (const float*)d_in[0];
    const float* Wq = (const float*)d_in[1];
    const float* Wk = (const float*)d_in[2];
    const float* Wv = (const float*)d_in[3];
    const float* Wc = (const float*)d_in[4];
    const float* bc = (const float*)d_in[5];
    float* out = (float*)d_out;

    const size_t PL   = (size_t)M_TOT * C_DIM;   // 8,388,608
    const size_t WQKV = (size_t)3072 * 1024;
    const size_t WC   = (size_t)1024 * 1024;

    ushort* ws   = (ushort*)d_ws;
    ushort* xh   = ws;
    ushort* xl   = xh + PL;
    ushort* WTh  = xl + PL;
    ushort* WTl  = WTh + WQKV;
    ushort* WcTh = WTl + WQKV;
    ushort* WcTl = WcTh + WC;
    ushort* Qh   = WcTl + WC;
    ushort* Kh   = Qh + PL;
    ushort* Vt   = Kh + PL;
    ushort* Ohh  = Vt + PL;
    ushort* Ohl  = Ohh + PL;

    decomp_x<<<4096, 256, 0, stream>>>(x, xh, xl);
    wtrans<<<dim3(16, 16, 4), 256, 0, stream>>>(Wq, Wk, Wv, Wc, WTh, WTl, WcTh, WcTl);
    qkv_mfma<<<dim3(M_TOT / 128, 24), 256, 0, stream>>>(xh, xl, WTh, WTl, Qh, Kh, Vt);
    attn_kernel<<<dim3(T_DIM / 64, BHT), 256, 0, stream>>>(Qh, Kh, Vt, Ohh, Ohl);
    out_mfma<<<dim3(M_TOT / 128, C_DIM / 128), 256, 0, stream>>>(Ohh, Ohl, WcTh, WcTl, bc, out);
}

// Round 12
// 363.844 us; speedup vs baseline: 10.5618x; 1.1831x over previous
//
#include <hip/hip_runtime.h>
#include <hip/hip_bf16.h>
#include <math.h>

// B=4, T=2048, C=1024, H=16, HD=64, M = B*T = 8192
// ws (ushort units, 128 MiB total):
//   xh,xl [8192][1024] | WTh,WTl [3072][1024] | WcTh,WcTl [1024][1024]
//   Qh,Kh [64][2048][64] | Vt [64][64][2048] | Ohh,Ohl [64][2048][64]
// (WTl/WcTl slots unused since the 2-term split.)

#define M_TOT   8192
#define C_DIM   1024
#define T_DIM   2048
#define NH      16
#define HD      64
#define BHT     (NH * 4)        // B*H = 64

typedef short  bf16x8 __attribute__((ext_vector_type(8)));
typedef ushort u16x8  __attribute__((ext_vector_type(8)));
typedef float  f32x4  __attribute__((ext_vector_type(4)));

static __device__ __forceinline__ ushort f2bf(float f) {
    union { __hip_bfloat16 h; ushort u; } cv;
    cv.h = __float2bfloat16(f);
    return cv.u;
}
static __device__ __forceinline__ float bf2f(ushort u) {
    union { ushort u; __hip_bfloat16 h; } cv;
    cv.u = u;
    return __bfloat162float(cv.h);
}
static __device__ __forceinline__ void gload16(const ushort* g, ushort* l) {
    __builtin_amdgcn_global_load_lds(
        (const __attribute__((address_space(1))) void*)g,
        (__attribute__((address_space(3))) void*)l, 16, 0, 0);
}

// ---------------------------------------------------------------------------
// Decomp 1: x fp32 -> xh/xl bf16 (hi/lo split). 8 elems/thread.
// ---------------------------------------------------------------------------
__global__ __launch_bounds__(256) void decomp_x(
    const float* __restrict__ x, ushort* __restrict__ xh, ushort* __restrict__ xl)
{
    const int i = blockIdx.x * 256 + threadIdx.x;
    const float4 a = ((const float4*)x)[2 * i];
    const float4 b = ((const float4*)x)[2 * i + 1];
    const float v[8] = {a.x, a.y, a.z, a.w, b.x, b.y, b.z, b.w};
    u16x8 h, l;
    #pragma unroll
    for (int e = 0; e < 8; ++e) {
        h[e] = f2bf(v[e]);
        l[e] = f2bf(v[e] - bf2f(h[e]));
    }
    ((u16x8*)xh)[i] = h;
    ((u16x8*)xl)[i] = l;
}

// ---------------------------------------------------------------------------
// Decomp 2: transpose W (fp32 [1024][1024]) -> WT bf16 [n][k], HI plane only
// (2-term split: W-low rounding term is below the bf16 output rounding).
// ---------------------------------------------------------------------------
__global__ __launch_bounds__(256) void wtrans(
    const float* __restrict__ Wq, const float* __restrict__ Wk,
    const float* __restrict__ Wv, const float* __restrict__ Wc,
    ushort* __restrict__ WTh, ushort* __restrict__ WcTh)
{
    __shared__ float tile[64][65];
    const int z = blockIdx.z;
    const float* W = (z == 0) ? Wq : (z == 1) ? Wk : (z == 2) ? Wv : Wc;
    const int n0 = blockIdx.x * 64, k0 = blockIdx.y * 64;
    const int tid = threadIdx.x;

    #pragma unroll
    for (int i = 0; i < 4; ++i) {
        const int lin = i * 1024 + tid * 4;
        const int r = lin >> 6, c = lin & 63;
        const float4 v = *(const float4*)(W + (size_t)(k0 + r) * 1024 + n0 + c);
        tile[r][c] = v.x; tile[r][c + 1] = v.y; tile[r][c + 2] = v.z; tile[r][c + 3] = v.w;
    }
    __syncthreads();

    ushort* oh = (z < 3) ? WTh : WcTh;
    const size_t rowbase = (z < 3) ? (size_t)z * 1024 : 0;
    #pragma unroll
    for (int i = 0; i < 4; ++i) {
        const int lin = i * 1024 + tid * 4;
        const int rn = lin >> 6, ck = lin & 63;
        ushort4 hv;
        hv.x = f2bf(tile[ck + 0][rn]);
        hv.y = f2bf(tile[ck + 1][rn]);
        hv.z = f2bf(tile[ck + 2][rn]);
        hv.w = f2bf(tile[ck + 3][rn]);
        *(ushort4*)(oh + (rowbase + n0 + rn) * 1024 + k0 + ck) = hv;
    }
}

// ---------------------------------------------------------------------------
// Kernel 1: QKV projection, bf16 MFMA, 2-term split (AhBh + AlBh).
// 128x128 tile, BK=64, 4 waves x (64x64), global_load_lds staging.
// LDS 48 KB -> 3 blocks/CU. Outputs Q/K head-major bf16, V transposed bf16.
// ---------------------------------------------------------------------------
__global__ __launch_bounds__(256, 3) void qkv_mfma(
    const ushort* __restrict__ xh, const ushort* __restrict__ xl,
    const ushort* __restrict__ WTh,
    ushort* __restrict__ Qh, ushort* __restrict__ Kh, ushort* __restrict__ Vt)
{
    __shared__ ushort Ah[128 * 64], Al[128 * 64], Bh[128 * 64]; // 48 KB

    const int tid = threadIdx.x;
    const int wave = tid >> 6, lane = tid & 63, lq = lane & 15, g = lane >> 4;
    const int m0 = blockIdx.x * 128;
    const int n0 = blockIdx.y * 128;            // over WT rows (3072)
    const int wm = wave >> 1, wn = wave & 1;
    const int sm = tid >> 3;
    const int sk = (tid & 7) * 8;

    f32x4 acc[4][4];
    #pragma unroll
    for (int i = 0; i < 4; ++i)
        #pragma unroll
        for (int j = 0; j < 4; ++j) { acc[i][j][0]=0.f; acc[i][j][1]=0.f; acc[i][j][2]=0.f; acc[i][j][3]=0.f; }

    for (int kt = 0; kt < 16; ++kt) {
        const int ko = kt * 64 + sk;
        #pragma unroll
        for (int rd = 0; rd < 4; ++rd) {
            const int mm = sm + rd * 32;
            const int lo = rd * 2048 + wave * 512;
            gload16(xh  + (size_t)(m0 + mm) * 1024 + ko, &Ah[lo]);
            gload16(xl  + (size_t)(m0 + mm) * 1024 + ko, &Al[lo]);
            gload16(WTh + (size_t)(n0 + mm) * 1024 + ko, &Bh[lo]);
        }
        __syncthreads();

        #pragma unroll
        for (int kc = 0; kc < 2; ++kc) {
            bf16x8 bhf[4];
            #pragma unroll
            for (int ni = 0; ni < 4; ++ni) {
                const int row = wn * 64 + ni * 16 + lq;
                bhf[ni] = *(const bf16x8*)&Bh[row * 64 + kc * 32 + g * 8];
            }
            #pragma unroll
            for (int mi = 0; mi < 4; ++mi) {
                const int row = wm * 64 + mi * 16 + lq;
                const bf16x8 ahf = *(const bf16x8*)&Ah[row * 64 + kc * 32 + g * 8];
                const bf16x8 alf = *(const bf16x8*)&Al[row * 64 + kc * 32 + g * 8];
                #pragma unroll
                for (int ni = 0; ni < 4; ++ni) {
                    acc[mi][ni] = __builtin_amdgcn_mfma_f32_16x16x32_bf16(ahf, bhf[ni], acc[mi][ni], 0, 0, 0);
                    acc[mi][ni] = __builtin_amdgcn_mfma_f32_16x16x32_bf16(alf, bhf[ni], acc[mi][ni], 0, 0, 0);
                }
            }
        }
        __syncthreads();
    }

    const int which = n0 >> 10;                 // 0=Q,1=K,2=V
    const int nn0 = n0 & 1023;
    const int b = m0 >> 11;
    const int tb = (m0 & 2047) + wm * 64;
    if (which < 2) {
        ushort* out = which ? Kh : Qh;
        #pragma unroll
        for (int mi = 0; mi < 4; ++mi) {
            const int t = tb + mi * 16 + g * 4;
            #pragma unroll
            for (int ni = 0; ni < 4; ++ni) {
                const int n = nn0 + wn * 64 + ni * 16 + lq;
                const int h = n >> 6, d = n & 63;
                ushort* op = out + ((size_t)(b * NH + h) * T_DIM + t) * HD + d;
                #pragma unroll
                for (int r = 0; r < 4; ++r) op[r * HD] = f2bf(acc[mi][ni][r]);
            }
        }
    } else {
        #pragma unroll
        for (int mi = 0; mi < 4; ++mi) {
            const int t = tb + mi * 16 + g * 4;
            #pragma unroll
            for (int ni = 0; ni < 4; ++ni) {
                const int n = nn0 + wn * 64 + ni * 16 + lq;
                const int h = n >> 6, d = n & 63;
                ushort4 v;
                v.x = f2bf(acc[mi][ni][0]); v.y = f2bf(acc[mi][ni][1]);
                v.z = f2bf(acc[mi][ni][2]); v.w = f2bf(acc[mi][ni][3]);
                *(ushort4*)(Vt + ((size_t)(b * NH + h) * HD + d) * T_DIM + t) = v;
            }
        }
    }
}

// ---------------------------------------------------------------------------
// Kernel 2: causal flash attention, bf16 MFMA, LDS-staged dbuf K/V.
// launch_bounds(256,4) (occupancy 2->4 blocks/CU was the R8 limiter),
// defer-max T13 (skip O-rescale when wave-wide max growth <= 8).
// ---------------------------------------------------------------------------
__global__ __launch_bounds__(256, 4) void attn_kernel(
    const ushort* __restrict__ Qh,
    const ushort* __restrict__ Kh,
    const ushort* __restrict__ Vt,
    ushort* __restrict__ Ohh,
    ushort* __restrict__ Ohl)
{
    __shared__ __align__(16) ushort sbuf[2][8192];   // K 0..4095 | V 4096..8191 per buf

    const int tid  = threadIdx.x;
    const int wave = tid >> 6, lane = tid & 63;
    const int lq   = lane & 15, g = lane >> 4;
    const int bh   = blockIdx.y;
    const int qt   = (T_DIM / 64 - 1) - blockIdx.x;   // heavy-first
    const int qw0  = qt * 64 + wave * 16;
    const int q    = qw0 + lq;
    const int ntiles = qt + 1;

    const ushort* Qb = Qh + ((size_t)bh * T_DIM + q) * HD;
    bf16x8 qf[2];
    qf[0] = *(const bf16x8*)(Qb + g * 8);
    qf[1] = *(const bf16x8*)(Qb + 32 + g * 8);

    const ushort* Kb = Kh + (size_t)bh * T_DIM * HD;
    const ushort* Vb = Vt + (size_t)bh * HD * T_DIM;

    const int srow  = tid >> 3;
    const int sunit = tid & 7;

    f32x4 o[4];
    #pragma unroll
    for (int dt = 0; dt < 4; ++dt) { o[dt][0]=0.f; o[dt][1]=0.f; o[dt][2]=0.f; o[dt][3]=0.f; }
    float m = -3.0e38f, l = 0.f;

    // prologue: stage tile 0 into buf 0 (inverse-swizzled global source)
    #pragma unroll
    for (int rr = 0; rr < 2; ++rr) {
        const int row = rr * 32 + srow;
        const int un  = sunit ^ (row & 7);
        gload16(Kb + (size_t)row * HD + un * 8,    &sbuf[0][rr * 2048 + wave * 512]);
        gload16(Vb + (size_t)row * T_DIM + un * 8, &sbuf[0][4096 + rr * 2048 + wave * 512]);
    }
    __syncthreads();

    int cur = 0;
    for (int kvt = 0; kvt < ntiles; ++kvt) {
        const bool lastt = (kvt == ntiles - 1);

        if (!lastt) {   // prefetch next tile into the other buffer
            const ushort* Kt  = Kb + (size_t)(kvt + 1) * 64 * HD;
            const ushort* Vtt = Vb + (kvt + 1) * 64;
            const int nb = cur ^ 1;
            #pragma unroll
            for (int rr = 0; rr < 2; ++rr) {
                const int row = rr * 32 + srow;
                const int un  = sunit ^ (row & 7);
                gload16(Kt + (size_t)row * HD + un * 8,     &sbuf[nb][rr * 2048 + wave * 512]);
                gload16(Vtt + (size_t)row * T_DIM + un * 8, &sbuf[nb][4096 + rr * 2048 + wave * 512]);
            }
        }

        const char* Ksb = (const char*)&sbuf[cur][0];
        const char* Vsb = (const char*)&sbuf[cur][4096];
        const int rxor = (lq & 7) << 4;

        bf16x8 kf[4][2];
        #pragma unroll
        for (int kt = 0; kt < 4; ++kt) {
            const int rb = (kt * 16 + lq) * 128;
            kf[kt][0] = *(const bf16x8*)(Ksb + rb + ((g * 16) ^ rxor));
            kf[kt][1] = *(const bf16x8*)(Ksb + rb + ((64 + g * 16) ^ rxor));
        }
        bf16x8 vf[4][2];
        #pragma unroll
        for (int dt = 0; dt < 4; ++dt) {
            const int rb = (dt * 16 + lq) * 128;
            #pragma unroll
            for (int cc = 0; cc < 2; ++cc) {
                ushort4 lo = *(const ushort4*)(Vsb + rb + ((cc * 64 + g * 8) ^ rxor));
                ushort4 hi = *(const ushort4*)(Vsb + rb + ((cc * 64 + g * 8 + 32) ^ rxor));
                bf16x8 v;
                v[0] = (short)lo.x; v[1] = (short)lo.y; v[2] = (short)lo.z; v[3] = (short)lo.w;
                v[4] = (short)hi.x; v[5] = (short)hi.y; v[6] = (short)hi.z; v[7] = (short)hi.w;
                vf[dt][cc] = v;
            }
        }

        // S^T = K · Q^T
        __builtin_amdgcn_s_setprio(1);
        f32x4 s[4];
        #pragma unroll
        for (int kt = 0; kt < 4; ++kt) {
            f32x4 z; z[0]=0.f; z[1]=0.f; z[2]=0.f; z[3]=0.f;
            z = __builtin_amdgcn_mfma_f32_16x16x32_bf16(kf[kt][0], qf[0], z, 0, 0, 0);
            s[kt] = __builtin_amdgcn_mfma_f32_16x16x32_bf16(kf[kt][1], qf[1], z, 0, 0, 0);
        }
        __builtin_amdgcn_s_setprio(0);

        // online softmax (lane-local rows)
        float p[4][4];
        float pmax = -3.0e38f;
        #pragma unroll
        for (int kt = 0; kt < 4; ++kt) {
            #pragma unroll
            for (int r = 0; r < 4; ++r) {
                float v = s[kt][r] * 0.125f;
                if (lastt) {
                    const int kv = kvt * 64 + kt * 16 + g * 4 + r;
                    if (kv > q) v = -3.0e38f;
                }
                p[kt][r] = v;
                pmax = fmaxf(pmax, v);
            }
        }
        pmax = fmaxf(pmax, __shfl_xor(pmax, 16));
        pmax = fmaxf(pmax, __shfl_xor(pmax, 32));

        // defer-max (T13): only rescale when some row's max grew by > 8
        if (!__all(pmax - m <= 8.0f)) {
            const float mnew = fmaxf(m, pmax);
            const float cf = __expf(m - mnew);
            l *= cf;
            #pragma unroll
            for (int dt = 0; dt < 4; ++dt) {
                o[dt][0] *= cf; o[dt][1] *= cf; o[dt][2] *= cf; o[dt][3] *= cf;
            }
            m = mnew;
        }

        float rs = 0.f;
        #pragma unroll
        for (int kt = 0; kt < 4; ++kt) {
            #pragma unroll
            for (int r = 0; r < 4; ++r) {
                const float w = __expf(p[kt][r] - m);
                p[kt][r] = w;
                rs += w;
            }
        }
        rs += __shfl_xor(rs, 16);
        rs += __shfl_xor(rs, 32);
        l += rs;

        // pack P^T (same k-mapping as vf)
        bf16x8 pf[2];
        #pragma unroll
        for (int cc = 0; cc < 2; ++cc) {
            #pragma unroll
            for (int j = 0; j < 8; ++j)
                pf[cc][j] = (short)f2bf(p[cc * 2 + (j >> 2)][j & 3]);
        }

        // O^T += V^T · P^T
        __builtin_amdgcn_s_setprio(1);
        #pragma unroll
        for (int dt = 0; dt < 4; ++dt) {
            o[dt] = __builtin_amdgcn_mfma_f32_16x16x32_bf16(vf[dt][0], pf[0], o[dt], 0, 0, 0);
            o[dt] = __builtin_amdgcn_mfma_f32_16x16x32_bf16(vf[dt][1], pf[1], o[dt], 0, 0, 0);
        }
        __builtin_amdgcn_s_setprio(0);

        __syncthreads();   // drain prefetch + release current buffer
        cur ^= 1;
    }

    // epilogue: divide by l, transpose via LDS (reuse staging), bf16 hi/lo out
    float* olds = (float*)&sbuf[0][0];
    const float invl = 1.0f / l;
    #pragma unroll
    for (int dt = 0; dt < 4; ++dt) {
        #pragma unroll
        for (int r = 0; r < 4; ++r)
            olds[wave * 1088 + lq * 68 + dt * 16 + g * 4 + r] = o[dt][r] * invl;
    }
    #pragma unroll
    for (int pp = 0; pp < 4; ++pp) {
        const int qq = pp * 4 + g;
        const float4 v4 = *(const float4*)&olds[wave * 1088 + qq * 68 + lq * 4];
        ushort4 hv, lv;
        hv.x = f2bf(v4.x); lv.x = f2bf(v4.x - bf2f(hv.x));
        hv.y = f2bf(v4.y); lv.y = f2bf(v4.y - bf2f(hv.y));
        hv.z = f2bf(v4.z); lv.z = f2bf(v4.z - bf2f(hv.z));
        hv.w = f2bf(v4.w); lv.w = f2bf(v4.w - bf2f(hv.w));
        const size_t off = ((size_t)bh * T_DIM + qw0 + qq) * HD + lq * 4;
        *(ushort4*)(Ohh + off) = hv;
        *(ushort4*)(Ohl + off) = lv;
    }
}

// ---------------------------------------------------------------------------
// Kernel 3: output projection, 2-term split ((Ahh+Ahl) x WcTh). LDS 48 KB.
// ---------------------------------------------------------------------------
__global__ __launch_bounds__(256, 3) void out_mfma(
    const ushort* __restrict__ Ahh, const ushort* __restrict__ Ahl,
    const ushort* __restrict__ BTh,
    const float* __restrict__ bc, float* __restrict__ out)
{
    __shared__ ushort Ah[128 * 64], Al[128 * 64], Bh[128 * 64];

    const int tid = threadIdx.x;
    const int wave = tid >> 6, lane = tid & 63, lq = lane & 15, g = lane >> 4;
    const int m0 = blockIdx.x * 128;
    const int n0 = blockIdx.y * 128;
    const int wm = wave >> 1, wn = wave & 1;
    const int sm = tid >> 3;
    const int sk = (tid & 7) * 8;
    const int b = m0 >> 11, t0 = m0 & 2047;

    f32x4 acc[4][4];
    #pragma unroll
    for (int i = 0; i < 4; ++i)
        #pragma unroll
        for (int j = 0; j < 4; ++j) { acc[i][j][0]=0.f; acc[i][j][1]=0.f; acc[i][j][2]=0.f; acc[i][j][3]=0.f; }

    for (int kt = 0; kt < 16; ++kt) {
        const size_t abase = ((size_t)(b * NH + kt) * T_DIM + t0) * HD;
        #pragma unroll
        for (int rd = 0; rd < 4; ++rd) {
            const int mm = sm + rd * 32;
            const int lo = rd * 2048 + wave * 512;
            gload16(Ahh + abase + (size_t)mm * HD + sk, &Ah[lo]);
            gload16(Ahl + abase + (size_t)mm * HD + sk, &Al[lo]);
            gload16(BTh + (size_t)(n0 + mm) * 1024 + kt * 64 + sk, &Bh[lo]);
        }
        __syncthreads();

        #pragma unroll
        for (int kc = 0; kc < 2; ++kc) {
            bf16x8 bhf[4];
            #pragma unroll
            for (int ni = 0; ni < 4; ++ni) {
                const int row = wn * 64 + ni * 16 + lq;
                bhf[ni] = *(const bf16x8*)&Bh[row * 64 + kc * 32 + g * 8];
            }
            #pragma unroll
            for (int mi = 0; mi < 4; ++mi) {
                const int row = wm * 64 + mi * 16 + lq;
                const bf16x8 ahf = *(const bf16x8*)&Ah[row * 64 + kc * 32 + g * 8];
                const bf16x8 alf = *(const bf16x8*)&Al[row * 64 + kc * 32 + g * 8];
                #pragma unroll
                for (int ni = 0; ni < 4; ++ni) {
                    acc[mi][ni] = __builtin_amdgcn_mfma_f32_16x16x32_bf16(ahf, bhf[ni], acc[mi][ni], 0, 0, 0);
                    acc[mi][ni] = __builtin_amdgcn_mfma_f32_16x16x32_bf16(alf, bhf[ni], acc[mi][ni], 0, 0, 0);
                }
            }
        }
        __syncthreads();
    }

    #pragma unroll
    for (int ni = 0; ni < 4; ++ni) {
        const int n = n0 + wn * 64 + ni * 16 + lq;
        const float bias = bc[n];
        #pragma unroll
        for (int mi = 0; mi < 4; ++mi) {
            const int mrow = m0 + wm * 64 + mi * 16 + g * 4;
            #pragma unroll
            for (int r = 0; r < 4; ++r)
                out[(size_t)(mrow + r) * C_DIM + n] = acc[mi][ni][r] + bias;
        }
    }
}

// ---------------------------------------------------------------------------
extern "C" void kernel_launch(void* const* d_in, const int* in_sizes, int n_in,
                              void* d_out, int out_size, void* d_ws, size_t ws_size,
                              hipStream_t stream)
{
    const float* x  = (const float*)d_in[0];
    const float* Wq = (const float*)d_in[1];
    const float* Wk = (const float*)d_in[2];
    const float* Wv = (const float*)d_in[3];
    const float* Wc = (const float*)d_in[4];
    const float* bc = (const float*)d_in[5];
    float* out = (float*)d_out;

    const size_t PL   = (size_t)M_TOT * C_DIM;   // 8,388,608
    const size_t WQKV = (size_t)3072 * 1024;
    const size_t WC   = (size_t)1024 * 1024;

    ushort* ws   = (ushort*)d_ws;
    ushort* xh   = ws;
    ushort* xl   = xh + PL;
    ushort* WTh  = xl + PL;
    ushort* WTl  = WTh + WQKV;     // unused (2-term)
    ushort* WcTh = WTl + WQKV;
    ushort* WcTl = WcTh + WC;      // unused (2-term)
    ushort* Qh   = WcTl + WC;
    ushort* Kh   = Qh + PL;
    ushort* Vt   = Kh + PL;
    ushort* Ohh  = Vt + PL;
    ushort* Ohl  = Ohh + PL;

    decomp_x<<<4096, 256, 0, stream>>>(x, xh, xl);
    wtrans<<<dim3(16, 16, 4), 256, 0, stream>>>(Wq, Wk, Wv, Wc, WTh, WcTh);
    qkv_mfma<<<dim3(M_TOT / 128, 24), 256, 0, stream>>>(xh, xl, WTh, Qh, Kh, Vt);
    attn_kernel<<<dim3(T_DIM / 64, BHT), 256, 0, stream>>>(Qh, Kh, Vt, Ohh, Ohl);
    out_mfma<<<dim3(M_TOT / 128, C_DIM / 128), 256, 0, stream>>>(Ohh, Ohl, WcTh, bc, out);
}